// Round 8
// baseline (2495.873 us; speedup 1.0000x reference)
//
#include <hip/hip_runtime.h>

#define B_   16
#define N_   38
#define NT_  9
#define ET_  4
#define NE_  703
#define R_   741
#define L_   12
#define BR_  11856   // B_*R_

// ============================================================================
// Kernel A: sx[b,n,eo] = ((x @ emb_w^T) @ gc1_w^T)[b,n,eo]   (B*N blocks)
// ============================================================================
__global__ __launch_bounds__(128) void k_sx(const float* __restrict__ x,
                                            const float* __restrict__ emb_w,
                                            const float* __restrict__ gc1_w,
                                            float* __restrict__ sx)
{
  int bn = blockIdx.x;            // b*N + n
  int t  = threadIdx.x;
  __shared__ float xr[NT_];
  __shared__ float hx[NT_];
  if (t < NT_) xr[t] = x[bn*NT_ + t];
  __syncthreads();
  if (t < NT_) {
    float s = 0.f;
    #pragma unroll
    for (int u = 0; u < NT_; ++u) s += xr[u] * emb_w[t*NT_ + u];
    hx[t] = s;
  }
  __syncthreads();
  for (int eo = t; eo < 384; eo += 128) {
    float s = 0.f;
    #pragma unroll
    for (int u = 0; u < NT_; ++u) s += hx[u] * gc1_w[eo*NT_ + u];
    sx[bn*384 + eo] = s;
  }
}

// ============================================================================
// Kernel A2: transpose gc2_w/gc3_w into Wt[(which*3+e)*128 + k][o]  (coalesced:
// per W-load a wave's 32 c-lanes read one contiguous 512 B segment).
// ============================================================================
__global__ __launch_bounds__(128) void k_wt(const float* __restrict__ gc2_w,
                                            const float* __restrict__ gc3_w,
                                            float* __restrict__ Wt)
{
  int blk   = blockIdx.x;
  int which = blk / 384;
  int rem   = blk - which*384;
  int e     = rem >> 7;
  int k     = rem & 127;
  int o     = threadIdx.x;
  const float* src = which ? gc3_w : gc2_w;
  Wt[(((which*3 + e) << 7) + k)*128 + o] = src[((e << 7) + o)*128 + k];
}

// ============================================================================
// Kernel B: per-(b,r) RGCN, 256 threads.
//   c = tid&31 -> cols {4c..4c+3}; p = tid>>5 -> rows {p,p+8,p+16,p+24,p+32}
// Round-7 post-mortem: at 3 blocks/CU neither VALU (61%) nor LDS pipe binds —
// latency/barrier-bound. Round-8: S_l and H_l are NEVER live simultaneously
// (fused gemm consumes all of H into registers before the first S write;
// einsum consumes S before the next relu_store), so they SHARE one buffer.
// LDS 47.6 -> 26.7 KB -> 5-6 blocks/CU (20-24 waves/CU) with the identical
// per-wave instruction mix. One extra barrier before the gv=0 relu_store
// (eacc readers of SH must drain before overwrite).
// ============================================================================
__device__ __forceinline__ void fma4(float4& d, float a, const float4& s) {
  d.x += a*s.x; d.y += a*s.y; d.z += a*s.z; d.w += a*s.w;
}

// Fill single-e A buffers. A4_l[j*32 + p*4 + m] = row i=p+8m; A1_l[j*8+p] = row 32+p.
__device__ __forceinline__ void fill_A(const float* __restrict__ adj,
                                       const int* __restrict__ mask_edge,
                                       int b, int r, int e, int tid,
                                       float* __restrict__ A4_l,
                                       float* __restrict__ A1_l)
{
  for (int m = tid; m < 38*32; m += 256) {
    int j    = m >> 5;
    int slot = m & 31;
    int i    = (slot >> 2) + ((slot & 3) << 3);     // p + 8m  (< 38)
    float v  = 0.f;
    if (mask_edge[(r*N_ + i)*N_ + j]) v = adj[((b*ET_ + e)*N_ + i)*N_ + j];
    A4_l[m] = v;
  }
  for (int m = tid; m < 38*8; m += 256) {
    int j = m >> 3;
    int i = (m & 7) + 32;                            // rows 32..39
    float v = 0.f;
    if (i < N_ && mask_edge[(r*N_ + i)*N_ + j]) v = adj[((b*ET_ + e)*N_ + i)*N_ + j];
    A1_l[m] = v;
  }
}

__device__ __forceinline__ void eacc_m(const float* __restrict__ A4_l,
                                       const float* __restrict__ A1_l,
                                       const float* __restrict__ S_l,
                                       int p, int c,
                                       const int* __restrict__ mn,
                                       float4 d[5])
{
  #pragma unroll 2
  for (int j = 0; j < 38; ++j) {
    if (!mn[j]) continue;                             // uniform branch
    float4 s4 = *(const float4*)&S_l[(j << 7) + (c << 2)];  // 2-way alias, free
    float4 a4 = *(const float4*)&A4_l[(j << 5) + (p << 2)]; // broadcast
    float  a1 = A1_l[(j << 3) + p];                          // broadcast
    fma4(d[0], a4.x, s4); fma4(d[1], a4.y, s4); fma4(d[2], a4.z, s4);
    fma4(d[3], a4.w, s4); fma4(d[4], a1,   s4);
  }
}

__device__ __forceinline__ void eacc_u(const float* __restrict__ A4_l,
                                       const float* __restrict__ A1_l,
                                       const float* __restrict__ S_l,
                                       int p, int c,
                                       float4 d[5])
{
  #pragma unroll 4
  for (int j = 0; j < 38; ++j) {
    float4 s4 = *(const float4*)&S_l[(j << 7) + (c << 2)];
    float4 a4 = *(const float4*)&A4_l[(j << 5) + (p << 2)];
    float  a1 = A1_l[(j << 3) + p];
    fma4(d[0], a4.x, s4); fma4(d[1], a4.y, s4); fma4(d[2], a4.z, s4);
    fma4(d[3], a4.w, s4); fma4(d[4], a1,   s4);
  }
}

// One k-pass over H (=SH buffer) feeding all 3 edge-type accumulators.
__device__ __forceinline__ void gemm_fused(const float* __restrict__ H_l,
                                           const float* __restrict__ Wb, // Wt + gv*3*16384
                                           int p, int c, float4 g[3][5])
{
  #pragma unroll
  for (int e = 0; e < 3; ++e)
    #pragma unroll
    for (int q = 0; q < 5; ++q) { g[e][q].x = 0.f; g[e][q].y = 0.f; g[e][q].z = 0.f; g[e][q].w = 0.f; }
  #pragma unroll 1
  for (int k0 = 0; k0 < 128; k0 += 4) {
    float4 h0 = *(const float4*)&H_l[((p+ 0) << 7) + k0];   // broadcast, once
    float4 h1 = *(const float4*)&H_l[((p+ 8) << 7) + k0];
    float4 h2 = *(const float4*)&H_l[((p+16) << 7) + k0];
    float4 h3 = *(const float4*)&H_l[((p+24) << 7) + k0];
    float4 h4 = *(const float4*)&H_l[((p+32) << 7) + k0];
    #pragma unroll
    for (int e = 0; e < 3; ++e) {
      const float* We = &Wb[(e << 14) + (k0 << 7) + (c << 2)];
      float4 w0 = *(const float4*)&We[  0];   // lanes c: contiguous 512B
      float4 w1 = *(const float4*)&We[128];
      float4 w2 = *(const float4*)&We[256];
      float4 w3 = *(const float4*)&We[384];
      fma4(g[e][0], h0.x, w0); fma4(g[e][0], h0.y, w1); fma4(g[e][0], h0.z, w2); fma4(g[e][0], h0.w, w3);
      fma4(g[e][1], h1.x, w0); fma4(g[e][1], h1.y, w1); fma4(g[e][1], h1.z, w2); fma4(g[e][1], h1.w, w3);
      fma4(g[e][2], h2.x, w0); fma4(g[e][2], h2.y, w1); fma4(g[e][2], h2.z, w2); fma4(g[e][2], h2.w, w3);
      fma4(g[e][3], h3.x, w0); fma4(g[e][3], h3.y, w1); fma4(g[e][3], h3.z, w2); fma4(g[e][3], h3.w, w3);
      fma4(g[e][4], h4.x, w0); fma4(g[e][4], h4.y, w1); fma4(g[e][4], h4.z, w2); fma4(g[e][4], h4.w, w3);
    }
  }
}

__device__ __forceinline__ void relu_store(float* __restrict__ H_l, int p, int c,
                                           const float4 d[5])
{
  #pragma unroll
  for (int q = 0; q < 5; ++q) {
    float4 t;
    t.x = fmaxf(d[q].x, 0.f); t.y = fmaxf(d[q].y, 0.f);
    t.z = fmaxf(d[q].z, 0.f); t.w = fmaxf(d[q].w, 0.f);
    *(float4*)&H_l[((p + (q << 3)) << 7) + (c << 2)] = t;
  }
}

__global__ __launch_bounds__(256) void k_rgcn(
    const float* __restrict__ adj, const int* __restrict__ mask_node,
    const int* __restrict__ mask_edge, const int* __restrict__ isel,
    const float* __restrict__ sx, const float* __restrict__ Wt,
    float* __restrict__ sumE, float* __restrict__ sumSq,
    float* __restrict__ selw)
{
  const int br  = blockIdx.x;
  const int b   = br / R_;
  const int r   = br - b*R_;
  const int tid = threadIdx.x;
  const int c   = tid & 31;
  const int p   = tid >> 5;

  __shared__ __align__(16) float A4_l[38*32];    //  4864 B (single e)
  __shared__ __align__(16) float A1_l[38*8];     //  1216 B (single e)
  __shared__ __align__(16) float SH_l[40*128];   // 20480 B (S and H, time-shared)
  __shared__ int mn_l[40];

  if (tid < 40) mn_l[tid] = (tid < 38) ? mask_node[r*N_ + tid] : 0;
  __syncthreads();

  float4 d[5];
  #pragma unroll
  for (int q = 0; q < 5; ++q) { d[q].x = d[q].y = d[q].z = d[q].w = 0.f; }

  // ---------------- gconv 1 (S from masked global sx, float4) ----------------
  for (int e = 0; e < 3; ++e) {
    for (int idx = tid; idx < 40*32; idx += 256) {
      int j = idx >> 5, q4 = idx & 31;
      float4 v; v.x = v.y = v.z = v.w = 0.f;
      if (j < N_ && mn_l[j]) v = *(const float4*)&sx[(b*N_ + j)*384 + (e << 7) + (q4 << 2)];
      *(float4*)&SH_l[(j << 7) + (q4 << 2)] = v;
    }
    fill_A(adj, mask_edge, b, r, e, tid, A4_l, A1_l);
    __syncthreads();
    eacc_m(A4_l, A1_l, SH_l, p, c, mn_l, d);
    __syncthreads();                       // einsum done before S/A refill
  }
  relu_store(SH_l, p, c, d);               // SH now holds H (all 40 rows)
  __syncthreads();

  // ---------------- gconv 2 (gv=0) and gconv 3 (gv=1), fused-e gemm ---------
  for (int gv = 0; gv < 2; ++gv) {
    float4 g[3][5];
    gemm_fused(SH_l, &Wt[gv*49152], p, c, g);   // consumes ALL of H into regs
    #pragma unroll
    for (int q = 0; q < 5; ++q) { d[q].x = d[q].y = d[q].z = d[q].w = 0.f; }
    #pragma unroll
    for (int e = 0; e < 3; ++e) {
      __syncthreads();      // e=0: all threads past gemm H-reads; e>0: prior eacc done
      #pragma unroll
      for (int q = 0; q < 5; ++q)
        *(float4*)&SH_l[((p + (q << 3)) << 7) + (c << 2)] = g[e][q];
      fill_A(adj, mask_edge, b, r, e, tid, A4_l, A1_l);
      __syncthreads();
      eacc_u(A4_l, A1_l, SH_l, p, c, d);
    }
    if (gv == 0) {
      __syncthreads();      // eacc (e=2) readers of SH done before H overwrite
      relu_store(SH_l, p, c, d);
      __syncthreads();      // H visible before gv=1 gemm reads it
    }
  }
  __syncthreads();   // last einsum done before SH reuse below

  // ---------------- BN partials + edge node selection ----------------
  {
    float4 sA, sB;
    sA.x = d[0].x+d[1].x+d[2].x+d[3].x+d[4].x;
    sA.y = d[0].y+d[1].y+d[2].y+d[3].y+d[4].y;
    sA.z = d[0].z+d[1].z+d[2].z+d[3].z+d[4].z;
    sA.w = d[0].w+d[1].w+d[2].w+d[3].w+d[4].w;
    sB.x = d[0].x*d[0].x+d[1].x*d[1].x+d[2].x*d[2].x+d[3].x*d[3].x+d[4].x*d[4].x;
    sB.y = d[0].y*d[0].y+d[1].y*d[1].y+d[2].y*d[2].y+d[3].y*d[3].y+d[4].y*d[4].y;
    sB.z = d[0].z*d[0].z+d[1].z*d[1].z+d[2].z*d[2].z+d[3].z*d[3].z+d[4].z*d[4].z;
    sB.w = d[0].w*d[0].w+d[1].w*d[1].w+d[2].w*d[2].w+d[3].w*d[3].w+d[4].w*d[4].w;
    *(float4*)&SH_l[( p      << 7) + (c << 2)] = sA;   // rows 0..7  : sums
    *(float4*)&SH_l[((8 + p) << 7) + (c << 2)] = sB;   // rows 8..15 : squares
  }
  __syncthreads();
  {
    int o = tid & 127, half = tid >> 7;
    float t = 0.f;
    #pragma unroll
    for (int pp = 0; pp < 8; ++pp) t += SH_l[(((half << 3) + pp) << 7) + o];
    if (half == 0) sumE [br*128 + o] = t;
    else           sumSq[br*128 + o] = t;
  }
  if (r >= N_) {
    int k  = r - N_;
    int iu = isel[2*k], ju = isel[2*k+1];
    if (p == (iu & 7)) {
      int mu = iu >> 3;
      float4 v = d[0];
      if (mu == 1) v = d[1]; else if (mu == 2) v = d[2];
      else if (mu == 3) v = d[3]; else if (mu == 4) v = d[4];
      *(float4*)&selw[(((b*NE_ + k)*2 + 0) << 7) + (c << 2)] = v;
    }
    if (p == (ju & 7)) {
      int mu = ju >> 3;
      float4 v = d[0];
      if (mu == 1) v = d[1]; else if (mu == 2) v = d[2];
      else if (mu == 3) v = d[3]; else if (mu == 4) v = d[4];
      *(float4*)&selw[(((b*NE_ + k)*2 + 1) << 7) + (c << 2)] = v;
    }
  }
}

// ============================================================================
// BN statistics: two-stage deterministic f64 reduction
// ============================================================================
__global__ __launch_bounds__(256) void k_bn1(const float* __restrict__ sumE,
                                             const float* __restrict__ sumSq,
                                             double* __restrict__ part)
{
  int g = blockIdx.x;                 // 0..255, rows [g*47, g*47+47)
  int t = threadIdx.x;
  int o = t & 127, h = t >> 7;
  int lo = g*47;
  int hi = lo + 47; if (hi > BR_) hi = BR_;
  double a1 = 0.0, a2 = 0.0;
  for (int i = lo + h; i < hi; i += 2) {
    a1 += (double)sumE [i*128 + o];
    a2 += (double)sumSq[i*128 + o];
  }
  __shared__ double sh1[256], sh2[256];
  sh1[t] = a1; sh2[t] = a2;
  __syncthreads();
  if (h == 0) {
    part[g*128 + o]           = sh1[o] + sh1[128 + o];
    part[256*128 + g*128 + o] = sh2[o] + sh2[128 + o];
  }
}

__global__ __launch_bounds__(128) void k_bn2(const double* __restrict__ part,
                                             const float* __restrict__ gamma,
                                             const float* __restrict__ beta,
                                             float* __restrict__ bnsc,
                                             float* __restrict__ bnsh)
{
  int o = threadIdx.x;
  double s1 = 0.0, s2 = 0.0;
  for (int g = 0; g < 256; ++g) {
    s1 += part[g*128 + o];
    s2 += part[256*128 + g*128 + o];
  }
  double cnt = (double)BR_ * 38.0;
  double m   = s1 / cnt;
  double var = s2 / cnt - m*m;
  double rs  = 1.0 / sqrt(var + 1e-5);
  double sc  = (double)gamma[o] * rs;
  bnsc[o] = (float)sc;
  bnsh[o] = beta[o] - (float)(m * sc);
}

// ============================================================================
// Kernel D: node discretization loop -> circular shift of x_deq
// ============================================================================
__global__ __launch_bounds__(128) void k_node(
    const float* __restrict__ sumE, const float* __restrict__ bnsc,
    const float* __restrict__ bnsh,
    const float* __restrict__ w1, const float* __restrict__ b1,
    const float* __restrict__ w2, const float* __restrict__ b2,
    const float* __restrict__ x_deq, float* __restrict__ out)
{
  int blk = blockIdx.x;               // b*N + n
  int b   = blk / N_;
  int o   = threadIdx.x;
  __shared__ __align__(16) float xv[128];
  __shared__ __align__(16) float hb[128];
  __shared__ float lg[NT_];
  __shared__ int   P_s;
  int br = b*R_ + (blk - b*N_);       // r = n  (node replicas)
  xv[o] = sumE[br*128 + o]*bnsc[o] + 38.f*bnsh[o];
  if (o == 0) P_s = 0;
  __syncthreads();
  for (int l = 0; l < L_; ++l) {
    const float* wr = &w1[(l*128 + o)*128];
    float s = b1[l*128 + o];
    for (int k = 0; k < 128; k += 4) {
      float4 w4 = *(const float4*)&wr[k];
      s += w4.x*xv[k] + w4.y*xv[k+1] + w4.z*xv[k+2] + w4.w*xv[k+3];
    }
    hb[o] = tanhf(s);
    __syncthreads();
    if (o < NT_) {
      const float* w2r = &w2[(l*NT_ + o)*128];
      float s2 = b2[l*NT_ + o];
      for (int k = 0; k < 128; ++k) s2 += w2r[k]*hb[k];
      lg[o] = s2;
    }
    __syncthreads();
    if (o == 0) {
      int best = 0; float bv = lg[0];
      #pragma unroll
      for (int cc = 1; cc < NT_; ++cc) if (lg[cc] > bv) { bv = lg[cc]; best = cc; }
      P_s += best;
    }
    __syncthreads();
  }
  int P = P_s % NT_;
  if (o < NT_) {
    int srcc = o - P; if (srcc < 0) srcc += NT_;
    out[blk*NT_ + o] = x_deq[blk*NT_ + srcc];
  }
}

// ============================================================================
// Kernel E: edge discretization. hb row stride 132 (round-3 fix: 16-way
// conflict at stride 128 -> 3.2M SQ_LDS_BANK_CONFLICT in round 2).
// ============================================================================
__global__ __launch_bounds__(256) void k_edge(
    const float* __restrict__ sumE, const float* __restrict__ selw,
    const float* __restrict__ bnsc, const float* __restrict__ bnsh,
    const float* __restrict__ w1, const float* __restrict__ b1,
    const float* __restrict__ w2, const float* __restrict__ b2,
    const float* __restrict__ adj_deq, float* __restrict__ out)
{
  int k = blockIdx.x;                 // edge index 0..NE-1
  int t = threadIdx.x;
  int o = t & 127, g = t >> 7;
  __shared__ __align__(16) float xv[16][384];
  __shared__ __align__(16) float hb[16][132];
  __shared__ float lg[16][4];
  __shared__ int   Pf[16];

  for (int idx = t; idx < 16*128; idx += 256) {
    int b = idx >> 7, oo = idx & 127;
    float sc = bnsc[oo], sh = bnsh[oo];
    int base = ((b*NE_ + k)*2)*128;
    xv[b][oo]       = selw[base + oo]      *sc + sh;
    xv[b][128 + oo] = selw[base + 128 + oo]*sc + sh;
    xv[b][256 + oo] = sumE[(b*R_ + N_ + k)*128 + oo]*sc + 38.f*sh;
  }
  int Preg = 0;
  __syncthreads();

  for (int l = 0; l < L_; ++l) {
    float acc[8];
    #pragma unroll
    for (int bb = 0; bb < 8; ++bb) acc[bb] = b1[l*128 + o];
    const float* wr = &w1[(l*128 + o)*384];
    for (int kk = 0; kk < 384; kk += 4) {
      float4 w4 = *(const float4*)&wr[kk];
      #pragma unroll
      for (int bb = 0; bb < 8; ++bb) {
        float4 h4 = *(const float4*)&xv[g*8 + bb][kk];
        acc[bb] += w4.x*h4.x + w4.y*h4.y + w4.z*h4.z + w4.w*h4.w;
      }
    }
    #pragma unroll
    for (int bb = 0; bb < 8; ++bb) hb[g*8 + bb][o] = tanhf(acc[bb]);
    __syncthreads();
    if (t < 64) {
      int m = t >> 2, c = t & 3;
      const float* w2r = &w2[(l*ET_ + c)*128];
      float s2 = b2[l*ET_ + c];
      for (int kk = 0; kk < 128; ++kk) s2 += w2r[kk]*hb[m][kk];
      lg[m][c] = s2;
    }
    __syncthreads();
    if (t < 16) {
      int best = 0; float bv = lg[t][0];
      #pragma unroll
      for (int c = 1; c < ET_; ++c) if (lg[t][c] > bv) { bv = lg[t][c]; best = c; }
      Preg += best;
    }
    __syncthreads();
  }
  if (t < 16) Pf[t] = Preg & 3;       // mod 4
  __syncthreads();
  if (t < 64) {
    int m = t >> 2, c = t & 3;
    int srcc = c - Pf[m]; if (srcc < 0) srcc += ET_;
    out[(m*NE_ + k)*ET_ + c] = adj_deq[(m*NE_ + k)*ET_ + srcc];
  }
}

// ============================================================================
extern "C" void kernel_launch(void* const* d_in, const int* in_sizes, int n_in,
                              void* d_out, int out_size, void* d_ws, size_t ws_size,
                              hipStream_t stream)
{
  (void)in_sizes; (void)n_in; (void)out_size; (void)ws_size;

  const float* x         = (const float*)d_in[0];
  const float* adj       = (const float*)d_in[1];
  const float* x_deq     = (const float*)d_in[2];
  const float* adj_deq   = (const float*)d_in[3];
  const int*   mask_node = (const int*)d_in[4];
  const int*   mask_edge = (const int*)d_in[5];
  const int*   isel      = (const int*)d_in[6];
  const float* emb_w     = (const float*)d_in[7];
  const float* gc1_w     = (const float*)d_in[8];
  const float* gc2_w     = (const float*)d_in[9];
  const float* gc3_w     = (const float*)d_in[10];
  const float* bn_gamma  = (const float*)d_in[11];
  const float* bn_beta   = (const float*)d_in[12];
  const float* node_w1   = (const float*)d_in[13];
  const float* node_b1   = (const float*)d_in[14];
  const float* node_w2   = (const float*)d_in[15];
  const float* node_b2   = (const float*)d_in[16];
  const float* edge_w1   = (const float*)d_in[17];
  const float* edge_b1   = (const float*)d_in[18];
  const float* edge_w2   = (const float*)d_in[19];
  const float* edge_b2   = (const float*)d_in[20];

  float* out_f = (float*)d_out;

  // Workspace layout. Wt (393 KB) overlays the f64 `part` region (524 KB):
  // Wt is consumed by k_rgcn, which completes before k_bn1 writes part.
  float*  wsf   = (float*)d_ws;
  float*  sx    = wsf;                      // 608*384       = 233472
  float*  sumE  = sx    + 233472;           // 11856*128     = 1517568
  float*  sumSq = sumE  + 1517568;          // 1517568
  float*  selw  = sumSq + 1517568;          // 16*703*2*128  = 2879488
  float*  bnsc  = selw  + 2879488;          // 128
  float*  bnsh  = bnsc  + 128;              // 128
  double* part  = (double*)(bnsh + 128);    // 2*256*128 doubles
  float*  Wt    = (float*)part;             // 98304 floats (overlay, see above)

  k_wt  <<<768,    128, 0, stream>>>(gc2_w, gc3_w, Wt);
  k_sx  <<<B_*N_,  128, 0, stream>>>(x, emb_w, gc1_w, sx);
  k_rgcn<<<BR_,    256, 0, stream>>>(adj, mask_node, mask_edge, isel, sx,
                                     Wt, sumE, sumSq, selw);
  k_bn1 <<<256,    256, 0, stream>>>(sumE, sumSq, part);
  k_bn2 <<<1,      128, 0, stream>>>(part, bn_gamma, bn_beta, bnsc, bnsh);
  k_node<<<B_*N_,  128, 0, stream>>>(sumE, bnsc, bnsh, node_w1, node_b1,
                                     node_w2, node_b2, x_deq, out_f);
  k_edge<<<NE_,    256, 0, stream>>>(sumE, selw, bnsc, bnsh, edge_w1, edge_b1,
                                     edge_w2, edge_b2, adj_deq,
                                     out_f + B_*N_*NT_);
}

// Round 9
// 2241.675 us; speedup vs baseline: 1.1134x; 1.1134x over previous
//
#include <hip/hip_runtime.h>

#define B_   16
#define N_   38
#define NT_  9
#define ET_  4
#define NE_  703
#define R_   741
#define L_   12
#define BR_  11856   // B_*R_

// ============================================================================
// Kernel A: sx[b,n,eo] = ((x @ emb_w^T) @ gc1_w^T)[b,n,eo]   (B*N blocks)
// ============================================================================
__global__ __launch_bounds__(128) void k_sx(const float* __restrict__ x,
                                            const float* __restrict__ emb_w,
                                            const float* __restrict__ gc1_w,
                                            float* __restrict__ sx)
{
  int bn = blockIdx.x;            // b*N + n
  int t  = threadIdx.x;
  __shared__ float xr[NT_];
  __shared__ float hx[NT_];
  if (t < NT_) xr[t] = x[bn*NT_ + t];
  __syncthreads();
  if (t < NT_) {
    float s = 0.f;
    #pragma unroll
    for (int u = 0; u < NT_; ++u) s += xr[u] * emb_w[t*NT_ + u];
    hx[t] = s;
  }
  __syncthreads();
  for (int eo = t; eo < 384; eo += 128) {
    float s = 0.f;
    #pragma unroll
    for (int u = 0; u < NT_; ++u) s += hx[u] * gc1_w[eo*NT_ + u];
    sx[bn*384 + eo] = s;
  }
}

// ============================================================================
// Kernel A2: transpose gc2_w/gc3_w into Wt[(which*3+e)*128 + k][o]  (coalesced:
// per W-load a wave's 32 c-lanes read one contiguous 512 B segment).
// ============================================================================
__global__ __launch_bounds__(128) void k_wt(const float* __restrict__ gc2_w,
                                            const float* __restrict__ gc3_w,
                                            float* __restrict__ Wt)
{
  int blk   = blockIdx.x;
  int which = blk / 384;
  int rem   = blk - which*384;
  int e     = rem >> 7;
  int k     = rem & 127;
  int o     = threadIdx.x;
  const float* src = which ? gc3_w : gc2_w;
  Wt[(((which*3 + e) << 7) + k)*128 + o] = src[((e << 7) + o)*128 + k];
}

// ============================================================================
// Kernel B: per-(b,r) RGCN, 256 threads.
//   c = tid&31 -> cols {4c..4c+3}; p = tid>>5 -> rows {p,p+8,p+16,p+24,p+32}
// Round-8 post-mortem: rounds 5/7/8 all pin at 2.0-2.2ms / occ ~34% across
// very different LDS sizes & instr mixes -> binder is the BARRIER-STAGE
// structure: 9 scatter-fill stages (mask/adj reads hit ~64 lines/wave-instr)
// expose L2+TA latency inside barrier-bounded regions. Round-9:
//  (a) full 3-e A buffer kept resident (fills 9 -> 3); SH sharing keeps
//      LDS at 38.9KB -> 4 blocks/CU.
//  (b) register-prefetch: stage e+1's global loads issued before eacc(e),
//      LDS-written after the barrier -> scatter latency hidden under compute.
//  (c) adj loaded unconditionally + select (no dependent mask->adj chain).
// ============================================================================
__device__ __forceinline__ void fma4(float4& d, float a, const float4& s) {
  d.x += a*s.x; d.y += a*s.y; d.z += a*s.z; d.w += a*s.w;
}

// ---- A prefetch: global -> regs (av[5], a1v[2]) ----
__device__ __forceinline__ void ldA(const float* __restrict__ adj,
                                    const int* __restrict__ mask_edge,
                                    int b, int r, int e, int tid,
                                    float av[5], float a1v[2])
{
  #pragma unroll
  for (int t = 0; t < 5; ++t) {
    int m = tid + (t << 8);
    float v = 0.f;
    if (m < 1216) {
      int j = m >> 5, slot = m & 31;
      int i = (slot >> 2) + ((slot & 3) << 3);          // < 38
      int   msk = mask_edge[(r*N_ + i)*N_ + j];
      float a   = adj[((b*ET_ + e)*N_ + i)*N_ + j];     // unconditional
      v = msk ? a : 0.f;
    }
    av[t] = v;
  }
  #pragma unroll
  for (int t = 0; t < 2; ++t) {
    int m = tid + (t << 8);
    float v = 0.f;
    if (m < 304) {
      int j = m >> 3;
      int i = (m & 7) + 32;                             // 32..39
      if (i < N_) {
        int   msk = mask_edge[(r*N_ + i)*N_ + j];
        float a   = adj[((b*ET_ + e)*N_ + i)*N_ + j];
        v = msk ? a : 0.f;
      }
    }
    a1v[t] = v;
  }
}

// ---- A store: regs -> LDS (per-e slice) ----
__device__ __forceinline__ void stA(float* __restrict__ A4e,
                                    float* __restrict__ A1e, int tid,
                                    const float av[5], const float a1v[2])
{
  #pragma unroll
  for (int t = 0; t < 5; ++t) {
    int m = tid + (t << 8);
    if (m < 1216) A4e[m] = av[t];
  }
  #pragma unroll
  for (int t = 0; t < 2; ++t) {
    int m = tid + (t << 8);
    if (m < 304) A1e[m] = a1v[t];
  }
}

__device__ __forceinline__ void eacc_m(const float* __restrict__ A4e,
                                       const float* __restrict__ A1e,
                                       const float* __restrict__ S_l,
                                       int p, int c,
                                       const int* __restrict__ mn,
                                       float4 d[5])
{
  #pragma unroll 2
  for (int j = 0; j < 38; ++j) {
    if (!mn[j]) continue;                             // uniform branch
    float4 s4 = *(const float4*)&S_l[(j << 7) + (c << 2)];  // 2-way alias, free
    float4 a4 = *(const float4*)&A4e[(j << 5) + (p << 2)];  // broadcast
    float  a1 = A1e[(j << 3) + p];                           // broadcast
    fma4(d[0], a4.x, s4); fma4(d[1], a4.y, s4); fma4(d[2], a4.z, s4);
    fma4(d[3], a4.w, s4); fma4(d[4], a1,   s4);
  }
}

__device__ __forceinline__ void eacc_u(const float* __restrict__ A4e,
                                       const float* __restrict__ A1e,
                                       const float* __restrict__ S_l,
                                       int p, int c,
                                       float4 d[5])
{
  #pragma unroll 4
  for (int j = 0; j < 38; ++j) {
    float4 s4 = *(const float4*)&S_l[(j << 7) + (c << 2)];
    float4 a4 = *(const float4*)&A4e[(j << 5) + (p << 2)];
    float  a1 = A1e[(j << 3) + p];
    fma4(d[0], a4.x, s4); fma4(d[1], a4.y, s4); fma4(d[2], a4.z, s4);
    fma4(d[3], a4.w, s4); fma4(d[4], a1,   s4);
  }
}

// One k-pass over H (=SH buffer) feeding all 3 edge-type accumulators.
__device__ __forceinline__ void gemm_fused(const float* __restrict__ H_l,
                                           const float* __restrict__ Wb, // Wt + gv*3*16384
                                           int p, int c, float4 g[3][5])
{
  #pragma unroll
  for (int e = 0; e < 3; ++e)
    #pragma unroll
    for (int q = 0; q < 5; ++q) { g[e][q].x = 0.f; g[e][q].y = 0.f; g[e][q].z = 0.f; g[e][q].w = 0.f; }
  #pragma unroll 1
  for (int k0 = 0; k0 < 128; k0 += 4) {
    float4 h0 = *(const float4*)&H_l[((p+ 0) << 7) + k0];   // broadcast, once
    float4 h1 = *(const float4*)&H_l[((p+ 8) << 7) + k0];
    float4 h2 = *(const float4*)&H_l[((p+16) << 7) + k0];
    float4 h3 = *(const float4*)&H_l[((p+24) << 7) + k0];
    float4 h4 = *(const float4*)&H_l[((p+32) << 7) + k0];
    #pragma unroll
    for (int e = 0; e < 3; ++e) {
      const float* We = &Wb[(e << 14) + (k0 << 7) + (c << 2)];
      float4 w0 = *(const float4*)&We[  0];   // lanes c: contiguous 512B
      float4 w1 = *(const float4*)&We[128];
      float4 w2 = *(const float4*)&We[256];
      float4 w3 = *(const float4*)&We[384];
      fma4(g[e][0], h0.x, w0); fma4(g[e][0], h0.y, w1); fma4(g[e][0], h0.z, w2); fma4(g[e][0], h0.w, w3);
      fma4(g[e][1], h1.x, w0); fma4(g[e][1], h1.y, w1); fma4(g[e][1], h1.z, w2); fma4(g[e][1], h1.w, w3);
      fma4(g[e][2], h2.x, w0); fma4(g[e][2], h2.y, w1); fma4(g[e][2], h2.z, w2); fma4(g[e][2], h2.w, w3);
      fma4(g[e][3], h3.x, w0); fma4(g[e][3], h3.y, w1); fma4(g[e][3], h3.z, w2); fma4(g[e][3], h3.w, w3);
      fma4(g[e][4], h4.x, w0); fma4(g[e][4], h4.y, w1); fma4(g[e][4], h4.z, w2); fma4(g[e][4], h4.w, w3);
    }
  }
}

__device__ __forceinline__ void relu_store(float* __restrict__ H_l, int p, int c,
                                           const float4 d[5])
{
  #pragma unroll
  for (int q = 0; q < 5; ++q) {
    float4 t;
    t.x = fmaxf(d[q].x, 0.f); t.y = fmaxf(d[q].y, 0.f);
    t.z = fmaxf(d[q].z, 0.f); t.w = fmaxf(d[q].w, 0.f);
    *(float4*)&H_l[((p + (q << 3)) << 7) + (c << 2)] = t;
  }
}

__global__ __launch_bounds__(256) void k_rgcn(
    const float* __restrict__ adj, const int* __restrict__ mask_node,
    const int* __restrict__ mask_edge, const int* __restrict__ isel,
    const float* __restrict__ sx, const float* __restrict__ Wt,
    float* __restrict__ sumE, float* __restrict__ sumSq,
    float* __restrict__ selw)
{
  const int br  = blockIdx.x;
  const int b   = br / R_;
  const int r   = br - b*R_;
  const int tid = threadIdx.x;
  const int c   = tid & 31;
  const int p   = tid >> 5;

  __shared__ __align__(16) float A4_l[3*1216];   // 14592 B (all 3 e, resident)
  __shared__ __align__(16) float A1_l[3*304];    //  3648 B
  __shared__ __align__(16) float SH_l[40*128];   // 20480 B (S and H, time-shared)
  __shared__ int mn_l[40];

  if (tid < 40) mn_l[tid] = (tid < 38) ? mask_node[r*N_ + tid] : 0;

  float av[5], a1v[2];
  ldA(adj, mask_edge, b, r, 0, tid, av, a1v);    // prefetch e=0
  __syncthreads();                               // mn_l visible

  float4 d[5];
  #pragma unroll
  for (int q = 0; q < 5; ++q) { d[q].x = d[q].y = d[q].z = d[q].w = 0.f; }

  // ---------------- gconv 1: S-fill + A-fill(once) + einsum, pipelined ------
  for (int e = 0; e < 3; ++e) {
    for (int idx = tid; idx < 40*32; idx += 256) {
      int j = idx >> 5, q4 = idx & 31;
      float4 v; v.x = v.y = v.z = v.w = 0.f;
      if (j < N_ && mn_l[j]) v = *(const float4*)&sx[(b*N_ + j)*384 + (e << 7) + (q4 << 2)];
      *(float4*)&SH_l[(j << 7) + (q4 << 2)] = v;
    }
    stA(&A4_l[e*1216], &A1_l[e*304], tid, av, a1v);
    __syncthreads();
    if (e < 2) ldA(adj, mask_edge, b, r, e+1, tid, av, a1v);  // hide under eacc
    eacc_m(&A4_l[e*1216], &A1_l[e*304], SH_l, p, c, mn_l, d);
    __syncthreads();                       // einsum done before S refill
  }
  relu_store(SH_l, p, c, d);               // SH now holds H (all 40 rows)
  __syncthreads();

  // ---------------- gconv 2 (gv=0) and gconv 3 (gv=1), fused-e gemm ---------
  // A stays resident: these stages are pure LDS+VALU (no global scatter).
  for (int gv = 0; gv < 2; ++gv) {
    float4 g[3][5];
    gemm_fused(SH_l, &Wt[gv*49152], p, c, g);   // consumes ALL of H into regs
    #pragma unroll
    for (int q = 0; q < 5; ++q) { d[q].x = d[q].y = d[q].z = d[q].w = 0.f; }
    #pragma unroll
    for (int e = 0; e < 3; ++e) {
      __syncthreads();      // e=0: gemm H-reads done; e>0: prior eacc S-reads done
      #pragma unroll
      for (int q = 0; q < 5; ++q)
        *(float4*)&SH_l[((p + (q << 3)) << 7) + (c << 2)] = g[e][q];
      __syncthreads();
      eacc_u(&A4_l[e*1216], &A1_l[e*304], SH_l, p, c, d);
    }
    if (gv == 0) {
      __syncthreads();      // eacc (e=2) readers of SH done before H overwrite
      relu_store(SH_l, p, c, d);
      __syncthreads();      // H visible before gv=1 gemm reads it
    }
  }
  __syncthreads();   // last einsum done before SH reuse below

  // ---------------- BN partials + edge node selection ----------------
  {
    float4 sA, sB;
    sA.x = d[0].x+d[1].x+d[2].x+d[3].x+d[4].x;
    sA.y = d[0].y+d[1].y+d[2].y+d[3].y+d[4].y;
    sA.z = d[0].z+d[1].z+d[2].z+d[3].z+d[4].z;
    sA.w = d[0].w+d[1].w+d[2].w+d[3].w+d[4].w;
    sB.x = d[0].x*d[0].x+d[1].x*d[1].x+d[2].x*d[2].x+d[3].x*d[3].x+d[4].x*d[4].x;
    sB.y = d[0].y*d[0].y+d[1].y*d[1].y+d[2].y*d[2].y+d[3].y*d[3].y+d[4].y*d[4].y;
    sB.z = d[0].z*d[0].z+d[1].z*d[1].z+d[2].z*d[2].z+d[3].z*d[3].z+d[4].z*d[4].z;
    sB.w = d[0].w*d[0].w+d[1].w*d[1].w+d[2].w*d[2].w+d[3].w*d[3].w+d[4].w*d[4].w;
    *(float4*)&SH_l[( p      << 7) + (c << 2)] = sA;   // rows 0..7  : sums
    *(float4*)&SH_l[((8 + p) << 7) + (c << 2)] = sB;   // rows 8..15 : squares
  }
  __syncthreads();
  {
    int o = tid & 127, half = tid >> 7;
    float t = 0.f;
    #pragma unroll
    for (int pp = 0; pp < 8; ++pp) t += SH_l[(((half << 3) + pp) << 7) + o];
    if (half == 0) sumE [br*128 + o] = t;
    else           sumSq[br*128 + o] = t;
  }
  if (r >= N_) {
    int k  = r - N_;
    int iu = isel[2*k], ju = isel[2*k+1];
    if (p == (iu & 7)) {
      int mu = iu >> 3;
      float4 v = d[0];
      if (mu == 1) v = d[1]; else if (mu == 2) v = d[2];
      else if (mu == 3) v = d[3]; else if (mu == 4) v = d[4];
      *(float4*)&selw[(((b*NE_ + k)*2 + 0) << 7) + (c << 2)] = v;
    }
    if (p == (ju & 7)) {
      int mu = ju >> 3;
      float4 v = d[0];
      if (mu == 1) v = d[1]; else if (mu == 2) v = d[2];
      else if (mu == 3) v = d[3]; else if (mu == 4) v = d[4];
      *(float4*)&selw[(((b*NE_ + k)*2 + 1) << 7) + (c << 2)] = v;
    }
  }
}

// ============================================================================
// BN statistics: two-stage deterministic f64 reduction
// ============================================================================
__global__ __launch_bounds__(256) void k_bn1(const float* __restrict__ sumE,
                                             const float* __restrict__ sumSq,
                                             double* __restrict__ part)
{
  int g = blockIdx.x;                 // 0..255, rows [g*47, g*47+47)
  int t = threadIdx.x;
  int o = t & 127, h = t >> 7;
  int lo = g*47;
  int hi = lo + 47; if (hi > BR_) hi = BR_;
  double a1 = 0.0, a2 = 0.0;
  for (int i = lo + h; i < hi; i += 2) {
    a1 += (double)sumE [i*128 + o];
    a2 += (double)sumSq[i*128 + o];
  }
  __shared__ double sh1[256], sh2[256];
  sh1[t] = a1; sh2[t] = a2;
  __syncthreads();
  if (h == 0) {
    part[g*128 + o]           = sh1[o] + sh1[128 + o];
    part[256*128 + g*128 + o] = sh2[o] + sh2[128 + o];
  }
}

__global__ __launch_bounds__(128) void k_bn2(const double* __restrict__ part,
                                             const float* __restrict__ gamma,
                                             const float* __restrict__ beta,
                                             float* __restrict__ bnsc,
                                             float* __restrict__ bnsh)
{
  int o = threadIdx.x;
  double s1 = 0.0, s2 = 0.0;
  for (int g = 0; g < 256; ++g) {
    s1 += part[g*128 + o];
    s2 += part[256*128 + g*128 + o];
  }
  double cnt = (double)BR_ * 38.0;
  double m   = s1 / cnt;
  double var = s2 / cnt - m*m;
  double rs  = 1.0 / sqrt(var + 1e-5);
  double sc  = (double)gamma[o] * rs;
  bnsc[o] = (float)sc;
  bnsh[o] = beta[o] - (float)(m * sc);
}

// ============================================================================
// Kernel D: node discretization loop -> circular shift of x_deq
// ============================================================================
__global__ __launch_bounds__(128) void k_node(
    const float* __restrict__ sumE, const float* __restrict__ bnsc,
    const float* __restrict__ bnsh,
    const float* __restrict__ w1, const float* __restrict__ b1,
    const float* __restrict__ w2, const float* __restrict__ b2,
    const float* __restrict__ x_deq, float* __restrict__ out)
{
  int blk = blockIdx.x;               // b*N + n
  int b   = blk / N_;
  int o   = threadIdx.x;
  __shared__ __align__(16) float xv[128];
  __shared__ __align__(16) float hb[128];
  __shared__ float lg[NT_];
  __shared__ int   P_s;
  int br = b*R_ + (blk - b*N_);       // r = n  (node replicas)
  xv[o] = sumE[br*128 + o]*bnsc[o] + 38.f*bnsh[o];
  if (o == 0) P_s = 0;
  __syncthreads();
  for (int l = 0; l < L_; ++l) {
    const float* wr = &w1[(l*128 + o)*128];
    float s = b1[l*128 + o];
    for (int k = 0; k < 128; k += 4) {
      float4 w4 = *(const float4*)&wr[k];
      s += w4.x*xv[k] + w4.y*xv[k+1] + w4.z*xv[k+2] + w4.w*xv[k+3];
    }
    hb[o] = tanhf(s);
    __syncthreads();
    if (o < NT_) {
      const float* w2r = &w2[(l*NT_ + o)*128];
      float s2 = b2[l*NT_ + o];
      for (int k = 0; k < 128; ++k) s2 += w2r[k]*hb[k];
      lg[o] = s2;
    }
    __syncthreads();
    if (o == 0) {
      int best = 0; float bv = lg[0];
      #pragma unroll
      for (int cc = 1; cc < NT_; ++cc) if (lg[cc] > bv) { bv = lg[cc]; best = cc; }
      P_s += best;
    }
    __syncthreads();
  }
  int P = P_s % NT_;
  if (o < NT_) {
    int srcc = o - P; if (srcc < 0) srcc += NT_;
    out[blk*NT_ + o] = x_deq[blk*NT_ + srcc];
  }
}

// ============================================================================
// Kernel E: edge discretization. hb row stride 132 (round-3 fix: 16-way
// conflict at stride 128 -> 3.2M SQ_LDS_BANK_CONFLICT in round 2).
// ============================================================================
__global__ __launch_bounds__(256) void k_edge(
    const float* __restrict__ sumE, const float* __restrict__ selw,
    const float* __restrict__ bnsc, const float* __restrict__ bnsh,
    const float* __restrict__ w1, const float* __restrict__ b1,
    const float* __restrict__ w2, const float* __restrict__ b2,
    const float* __restrict__ adj_deq, float* __restrict__ out)
{
  int k = blockIdx.x;                 // edge index 0..NE-1
  int t = threadIdx.x;
  int o = t & 127, g = t >> 7;
  __shared__ __align__(16) float xv[16][384];
  __shared__ __align__(16) float hb[16][132];
  __shared__ float lg[16][4];
  __shared__ int   Pf[16];

  for (int idx = t; idx < 16*128; idx += 256) {
    int b = idx >> 7, oo = idx & 127;
    float sc = bnsc[oo], sh = bnsh[oo];
    int base = ((b*NE_ + k)*2)*128;
    xv[b][oo]       = selw[base + oo]      *sc + sh;
    xv[b][128 + oo] = selw[base + 128 + oo]*sc + sh;
    xv[b][256 + oo] = sumE[(b*R_ + N_ + k)*128 + oo]*sc + 38.f*sh;
  }
  int Preg = 0;
  __syncthreads();

  for (int l = 0; l < L_; ++l) {
    float acc[8];
    #pragma unroll
    for (int bb = 0; bb < 8; ++bb) acc[bb] = b1[l*128 + o];
    const float* wr = &w1[(l*128 + o)*384];
    for (int kk = 0; kk < 384; kk += 4) {
      float4 w4 = *(const float4*)&wr[kk];
      #pragma unroll
      for (int bb = 0; bb < 8; ++bb) {
        float4 h4 = *(const float4*)&xv[g*8 + bb][kk];
        acc[bb] += w4.x*h4.x + w4.y*h4.y + w4.z*h4.z + w4.w*h4.w;
      }
    }
    #pragma unroll
    for (int bb = 0; bb < 8; ++bb) hb[g*8 + bb][o] = tanhf(acc[bb]);
    __syncthreads();
    if (t < 64) {
      int m = t >> 2, c = t & 3;
      const float* w2r = &w2[(l*ET_ + c)*128];
      float s2 = b2[l*ET_ + c];
      for (int kk = 0; kk < 128; ++kk) s2 += w2r[kk]*hb[m][kk];
      lg[m][c] = s2;
    }
    __syncthreads();
    if (t < 16) {
      int best = 0; float bv = lg[t][0];
      #pragma unroll
      for (int c = 1; c < ET_; ++c) if (lg[t][c] > bv) { bv = lg[t][c]; best = c; }
      Preg += best;
    }
    __syncthreads();
  }
  if (t < 16) Pf[t] = Preg & 3;       // mod 4
  __syncthreads();
  if (t < 64) {
    int m = t >> 2, c = t & 3;
    int srcc = c - Pf[m]; if (srcc < 0) srcc += ET_;
    out[(m*NE_ + k)*ET_ + c] = adj_deq[(m*NE_ + k)*ET_ + srcc];
  }
}

// ============================================================================
extern "C" void kernel_launch(void* const* d_in, const int* in_sizes, int n_in,
                              void* d_out, int out_size, void* d_ws, size_t ws_size,
                              hipStream_t stream)
{
  (void)in_sizes; (void)n_in; (void)out_size; (void)ws_size;

  const float* x         = (const float*)d_in[0];
  const float* adj       = (const float*)d_in[1];
  const float* x_deq     = (const float*)d_in[2];
  const float* adj_deq   = (const float*)d_in[3];
  const int*   mask_node = (const int*)d_in[4];
  const int*   mask_edge = (const int*)d_in[5];
  const int*   isel      = (const int*)d_in[6];
  const float* emb_w     = (const float*)d_in[7];
  const float* gc1_w     = (const float*)d_in[8];
  const float* gc2_w     = (const float*)d_in[9];
  const float* gc3_w     = (const float*)d_in[10];
  const float* bn_gamma  = (const float*)d_in[11];
  const float* bn_beta   = (const float*)d_in[12];
  const float* node_w1   = (const float*)d_in[13];
  const float* node_b1   = (const float*)d_in[14];
  const float* node_w2   = (const float*)d_in[15];
  const float* node_b2   = (const float*)d_in[16];
  const float* edge_w1   = (const float*)d_in[17];
  const float* edge_b1   = (const float*)d_in[18];
  const float* edge_w2   = (const float*)d_in[19];
  const float* edge_b2   = (const float*)d_in[20];

  float* out_f = (float*)d_out;

  // Workspace layout. Wt (393 KB) overlays the f64 `part` region (524 KB):
  // Wt is consumed by k_rgcn, which completes before k_bn1 writes part.
  float*  wsf   = (float*)d_ws;
  float*  sx    = wsf;                      // 608*384       = 233472
  float*  sumE  = sx    + 233472;           // 11856*128     = 1517568
  float*  sumSq = sumE  + 1517568;          // 1517568
  float*  selw  = sumSq + 1517568;          // 16*703*2*128  = 2879488
  float*  bnsc  = selw  + 2879488;          // 128
  float*  bnsh  = bnsc  + 128;              // 128
  double* part  = (double*)(bnsh + 128);    // 2*256*128 doubles
  float*  Wt    = (float*)part;             // 98304 floats (overlay, see above)

  k_wt  <<<768,    128, 0, stream>>>(gc2_w, gc3_w, Wt);
  k_sx  <<<B_*N_,  128, 0, stream>>>(x, emb_w, gc1_w, sx);
  k_rgcn<<<BR_,    256, 0, stream>>>(adj, mask_node, mask_edge, isel, sx,
                                     Wt, sumE, sumSq, selw);
  k_bn1 <<<256,    256, 0, stream>>>(sumE, sumSq, part);
  k_bn2 <<<1,      128, 0, stream>>>(part, bn_gamma, bn_beta, bnsc, bnsh);
  k_node<<<B_*N_,  128, 0, stream>>>(sumE, bnsc, bnsh, node_w1, node_b1,
                                     node_w2, node_b2, x_deq, out_f);
  k_edge<<<NE_,    256, 0, stream>>>(sumE, selw, bnsc, bnsh, edge_w1, edge_b1,
                                     edge_w2, edge_b2, adj_deq,
                                     out_f + B_*N_*NT_);
}

// Round 10
// 2208.925 us; speedup vs baseline: 1.1299x; 1.0148x over previous
//
#include <hip/hip_runtime.h>

#define B_   16
#define N_   38
#define NT_  9
#define ET_  4
#define NE_  703
#define R_   741
#define L_   12
#define BR_  11856   // B_*R_

// ============================================================================
// Kernel A: sx[b,n,eo] = ((x @ emb_w^T) @ gc1_w^T)[b,n,eo]   (B*N blocks)
// ============================================================================
__global__ __launch_bounds__(128) void k_sx(const float* __restrict__ x,
                                            const float* __restrict__ emb_w,
                                            const float* __restrict__ gc1_w,
                                            float* __restrict__ sx)
{
  int bn = blockIdx.x;            // b*N + n
  int t  = threadIdx.x;
  __shared__ float xr[NT_];
  __shared__ float hx[NT_];
  if (t < NT_) xr[t] = x[bn*NT_ + t];
  __syncthreads();
  if (t < NT_) {
    float s = 0.f;
    #pragma unroll
    for (int u = 0; u < NT_; ++u) s += xr[u] * emb_w[t*NT_ + u];
    hx[t] = s;
  }
  __syncthreads();
  for (int eo = t; eo < 384; eo += 128) {
    float s = 0.f;
    #pragma unroll
    for (int u = 0; u < NT_; ++u) s += hx[u] * gc1_w[eo*NT_ + u];
    sx[bn*384 + eo] = s;
  }
}

// ============================================================================
// Kernel A2: transpose gc2_w/gc3_w into Wt[(which*3+e)*128 + k][o]  (coalesced)
// ============================================================================
__global__ __launch_bounds__(128) void k_wt(const float* __restrict__ gc2_w,
                                            const float* __restrict__ gc3_w,
                                            float* __restrict__ Wt)
{
  int blk   = blockIdx.x;
  int which = blk / 384;
  int rem   = blk - which*384;
  int e     = rem >> 7;
  int k     = rem & 127;
  int o     = threadIdx.x;
  const float* src = which ? gc3_w : gc2_w;
  Wt[(((which*3 + e) << 7) + k)*128 + o] = src[((e << 7) + o)*128 + k];
}

// ============================================================================
// Kernel A3 (round-10): transpose node_w1/edge_w1 to [l][k][o] so the
// discretization kernels read weights COALESCED. The old per-lane-row layout
// made every weight load span 64 cache lines (w1[(l*128+o)*K + kk], lane
// stride 4K bytes) — the round-6 de-coalescing disaster, present in
// k_edge/k_node since round 0. Output overlays sumSq (dead after k_bn1);
// this kernel launches after k_bn1.
//   blk < 4608: edge rows (l,kk) ; else node rows (l,k). 128 threads = o.
// ============================================================================
__global__ __launch_bounds__(128) void k_wt2(const float* __restrict__ node_w1,
                                             const float* __restrict__ edge_w1,
                                             float* __restrict__ w1t_e,
                                             float* __restrict__ w1t_n)
{
  int blk = blockIdx.x;
  int o   = threadIdx.x;
  if (blk < 12*384) {
    int l = blk / 384, kk = blk - l*384;
    w1t_e[blk*128 + o] = edge_w1[(l*128 + o)*384 + kk];
  } else {
    int row = blk - 12*384;               // l*128 + k
    int l = row >> 7, k = row & 127;
    w1t_n[row*128 + o] = node_w1[(l*128 + o)*128 + k];
  }
}

// ============================================================================
// Kernel B: per-(b,r) RGCN, 256 threads.  (round-9 version, unchanged: 1.71ms,
// VALUBusy 76%, occ 45%, no spill — remaining headroom ~15% vs 0.86ms fma
// floor; all structural levers tried in rounds 4-8.)
//   c = tid&31 -> cols {4c..4c+3}; p = tid>>5 -> rows {p,p+8,p+16,p+24,p+32}
// ============================================================================
__device__ __forceinline__ void fma4(float4& d, float a, const float4& s) {
  d.x += a*s.x; d.y += a*s.y; d.z += a*s.z; d.w += a*s.w;
}

// ---- A prefetch: global -> regs (av[5], a1v[2]) ----
__device__ __forceinline__ void ldA(const float* __restrict__ adj,
                                    const int* __restrict__ mask_edge,
                                    int b, int r, int e, int tid,
                                    float av[5], float a1v[2])
{
  #pragma unroll
  for (int t = 0; t < 5; ++t) {
    int m = tid + (t << 8);
    float v = 0.f;
    if (m < 1216) {
      int j = m >> 5, slot = m & 31;
      int i = (slot >> 2) + ((slot & 3) << 3);          // < 38
      int   msk = mask_edge[(r*N_ + i)*N_ + j];
      float a   = adj[((b*ET_ + e)*N_ + i)*N_ + j];     // unconditional
      v = msk ? a : 0.f;
    }
    av[t] = v;
  }
  #pragma unroll
  for (int t = 0; t < 2; ++t) {
    int m = tid + (t << 8);
    float v = 0.f;
    if (m < 304) {
      int j = m >> 3;
      int i = (m & 7) + 32;                             // 32..39
      if (i < N_) {
        int   msk = mask_edge[(r*N_ + i)*N_ + j];
        float a   = adj[((b*ET_ + e)*N_ + i)*N_ + j];
        v = msk ? a : 0.f;
      }
    }
    a1v[t] = v;
  }
}

// ---- A store: regs -> LDS (per-e slice) ----
__device__ __forceinline__ void stA(float* __restrict__ A4e,
                                    float* __restrict__ A1e, int tid,
                                    const float av[5], const float a1v[2])
{
  #pragma unroll
  for (int t = 0; t < 5; ++t) {
    int m = tid + (t << 8);
    if (m < 1216) A4e[m] = av[t];
  }
  #pragma unroll
  for (int t = 0; t < 2; ++t) {
    int m = tid + (t << 8);
    if (m < 304) A1e[m] = a1v[t];
  }
}

__device__ __forceinline__ void eacc_m(const float* __restrict__ A4e,
                                       const float* __restrict__ A1e,
                                       const float* __restrict__ S_l,
                                       int p, int c,
                                       const int* __restrict__ mn,
                                       float4 d[5])
{
  #pragma unroll 2
  for (int j = 0; j < 38; ++j) {
    if (!mn[j]) continue;                             // uniform branch
    float4 s4 = *(const float4*)&S_l[(j << 7) + (c << 2)];  // 2-way alias, free
    float4 a4 = *(const float4*)&A4e[(j << 5) + (p << 2)];  // broadcast
    float  a1 = A1e[(j << 3) + p];                           // broadcast
    fma4(d[0], a4.x, s4); fma4(d[1], a4.y, s4); fma4(d[2], a4.z, s4);
    fma4(d[3], a4.w, s4); fma4(d[4], a1,   s4);
  }
}

__device__ __forceinline__ void eacc_u(const float* __restrict__ A4e,
                                       const float* __restrict__ A1e,
                                       const float* __restrict__ S_l,
                                       int p, int c,
                                       float4 d[5])
{
  #pragma unroll 4
  for (int j = 0; j < 38; ++j) {
    float4 s4 = *(const float4*)&S_l[(j << 7) + (c << 2)];
    float4 a4 = *(const float4*)&A4e[(j << 5) + (p << 2)];
    float  a1 = A1e[(j << 3) + p];
    fma4(d[0], a4.x, s4); fma4(d[1], a4.y, s4); fma4(d[2], a4.z, s4);
    fma4(d[3], a4.w, s4); fma4(d[4], a1,   s4);
  }
}

// One k-pass over H (=SH buffer) feeding all 3 edge-type accumulators.
__device__ __forceinline__ void gemm_fused(const float* __restrict__ H_l,
                                           const float* __restrict__ Wb, // Wt + gv*3*16384
                                           int p, int c, float4 g[3][5])
{
  #pragma unroll
  for (int e = 0; e < 3; ++e)
    #pragma unroll
    for (int q = 0; q < 5; ++q) { g[e][q].x = 0.f; g[e][q].y = 0.f; g[e][q].z = 0.f; g[e][q].w = 0.f; }
  #pragma unroll 1
  for (int k0 = 0; k0 < 128; k0 += 4) {
    float4 h0 = *(const float4*)&H_l[((p+ 0) << 7) + k0];   // broadcast, once
    float4 h1 = *(const float4*)&H_l[((p+ 8) << 7) + k0];
    float4 h2 = *(const float4*)&H_l[((p+16) << 7) + k0];
    float4 h3 = *(const float4*)&H_l[((p+24) << 7) + k0];
    float4 h4 = *(const float4*)&H_l[((p+32) << 7) + k0];
    #pragma unroll
    for (int e = 0; e < 3; ++e) {
      const float* We = &Wb[(e << 14) + (k0 << 7) + (c << 2)];
      float4 w0 = *(const float4*)&We[  0];   // lanes c: contiguous 512B
      float4 w1 = *(const float4*)&We[128];
      float4 w2 = *(const float4*)&We[256];
      float4 w3 = *(const float4*)&We[384];
      fma4(g[e][0], h0.x, w0); fma4(g[e][0], h0.y, w1); fma4(g[e][0], h0.z, w2); fma4(g[e][0], h0.w, w3);
      fma4(g[e][1], h1.x, w0); fma4(g[e][1], h1.y, w1); fma4(g[e][1], h1.z, w2); fma4(g[e][1], h1.w, w3);
      fma4(g[e][2], h2.x, w0); fma4(g[e][2], h2.y, w1); fma4(g[e][2], h2.z, w2); fma4(g[e][2], h2.w, w3);
      fma4(g[e][3], h3.x, w0); fma4(g[e][3], h3.y, w1); fma4(g[e][3], h3.z, w2); fma4(g[e][3], h3.w, w3);
      fma4(g[e][4], h4.x, w0); fma4(g[e][4], h4.y, w1); fma4(g[e][4], h4.z, w2); fma4(g[e][4], h4.w, w3);
    }
  }
}

__device__ __forceinline__ void relu_store(float* __restrict__ H_l, int p, int c,
                                           const float4 d[5])
{
  #pragma unroll
  for (int q = 0; q < 5; ++q) {
    float4 t;
    t.x = fmaxf(d[q].x, 0.f); t.y = fmaxf(d[q].y, 0.f);
    t.z = fmaxf(d[q].z, 0.f); t.w = fmaxf(d[q].w, 0.f);
    *(float4*)&H_l[((p + (q << 3)) << 7) + (c << 2)] = t;
  }
}

__global__ __launch_bounds__(256) void k_rgcn(
    const float* __restrict__ adj, const int* __restrict__ mask_node,
    const int* __restrict__ mask_edge, const int* __restrict__ isel,
    const float* __restrict__ sx, const float* __restrict__ Wt,
    float* __restrict__ sumE, float* __restrict__ sumSq,
    float* __restrict__ selw)
{
  const int br  = blockIdx.x;
  const int b   = br / R_;
  const int r   = br - b*R_;
  const int tid = threadIdx.x;
  const int c   = tid & 31;
  const int p   = tid >> 5;

  __shared__ __align__(16) float A4_l[3*1216];   // 14592 B (all 3 e, resident)
  __shared__ __align__(16) float A1_l[3*304];    //  3648 B
  __shared__ __align__(16) float SH_l[40*128];   // 20480 B (S and H, time-shared)
  __shared__ int mn_l[40];

  if (tid < 40) mn_l[tid] = (tid < 38) ? mask_node[r*N_ + tid] : 0;

  float av[5], a1v[2];
  ldA(adj, mask_edge, b, r, 0, tid, av, a1v);    // prefetch e=0
  __syncthreads();                               // mn_l visible

  float4 d[5];
  #pragma unroll
  for (int q = 0; q < 5; ++q) { d[q].x = d[q].y = d[q].z = d[q].w = 0.f; }

  // ---------------- gconv 1: S-fill + A-fill(once) + einsum, pipelined ------
  for (int e = 0; e < 3; ++e) {
    for (int idx = tid; idx < 40*32; idx += 256) {
      int j = idx >> 5, q4 = idx & 31;
      float4 v; v.x = v.y = v.z = v.w = 0.f;
      if (j < N_ && mn_l[j]) v = *(const float4*)&sx[(b*N_ + j)*384 + (e << 7) + (q4 << 2)];
      *(float4*)&SH_l[(j << 7) + (q4 << 2)] = v;
    }
    stA(&A4_l[e*1216], &A1_l[e*304], tid, av, a1v);
    __syncthreads();
    if (e < 2) ldA(adj, mask_edge, b, r, e+1, tid, av, a1v);  // hide under eacc
    eacc_m(&A4_l[e*1216], &A1_l[e*304], SH_l, p, c, mn_l, d);
    __syncthreads();                       // einsum done before S refill
  }
  relu_store(SH_l, p, c, d);               // SH now holds H (all 40 rows)
  __syncthreads();

  // ---------------- gconv 2 (gv=0) and gconv 3 (gv=1), fused-e gemm ---------
  for (int gv = 0; gv < 2; ++gv) {
    float4 g[3][5];
    gemm_fused(SH_l, &Wt[gv*49152], p, c, g);   // consumes ALL of H into regs
    #pragma unroll
    for (int q = 0; q < 5; ++q) { d[q].x = d[q].y = d[q].z = d[q].w = 0.f; }
    #pragma unroll
    for (int e = 0; e < 3; ++e) {
      __syncthreads();      // e=0: gemm H-reads done; e>0: prior eacc S-reads done
      #pragma unroll
      for (int q = 0; q < 5; ++q)
        *(float4*)&SH_l[((p + (q << 3)) << 7) + (c << 2)] = g[e][q];
      __syncthreads();
      eacc_u(&A4_l[e*1216], &A1_l[e*304], SH_l, p, c, d);
    }
    if (gv == 0) {
      __syncthreads();      // eacc (e=2) readers of SH done before H overwrite
      relu_store(SH_l, p, c, d);
      __syncthreads();      // H visible before gv=1 gemm reads it
    }
  }
  __syncthreads();   // last einsum done before SH reuse below

  // ---------------- BN partials + edge node selection ----------------
  {
    float4 sA, sB;
    sA.x = d[0].x+d[1].x+d[2].x+d[3].x+d[4].x;
    sA.y = d[0].y+d[1].y+d[2].y+d[3].y+d[4].y;
    sA.z = d[0].z+d[1].z+d[2].z+d[3].z+d[4].z;
    sA.w = d[0].w+d[1].w+d[2].w+d[3].w+d[4].w;
    sB.x = d[0].x*d[0].x+d[1].x*d[1].x+d[2].x*d[2].x+d[3].x*d[3].x+d[4].x*d[4].x;
    sB.y = d[0].y*d[0].y+d[1].y*d[1].y+d[2].y*d[2].y+d[3].y*d[3].y+d[4].y*d[4].y;
    sB.z = d[0].z*d[0].z+d[1].z*d[1].z+d[2].z*d[2].z+d[3].z*d[3].z+d[4].z*d[4].z;
    sB.w = d[0].w*d[0].w+d[1].w*d[1].w+d[2].w*d[2].w+d[3].w*d[3].w+d[4].w*d[4].w;
    *(float4*)&SH_l[( p      << 7) + (c << 2)] = sA;   // rows 0..7  : sums
    *(float4*)&SH_l[((8 + p) << 7) + (c << 2)] = sB;   // rows 8..15 : squares
  }
  __syncthreads();
  {
    int o = tid & 127, half = tid >> 7;
    float t = 0.f;
    #pragma unroll
    for (int pp = 0; pp < 8; ++pp) t += SH_l[(((half << 3) + pp) << 7) + o];
    if (half == 0) sumE [br*128 + o] = t;
    else           sumSq[br*128 + o] = t;
  }
  if (r >= N_) {
    int k  = r - N_;
    int iu = isel[2*k], ju = isel[2*k+1];
    if (p == (iu & 7)) {
      int mu = iu >> 3;
      float4 v = d[0];
      if (mu == 1) v = d[1]; else if (mu == 2) v = d[2];
      else if (mu == 3) v = d[3]; else if (mu == 4) v = d[4];
      *(float4*)&selw[(((b*NE_ + k)*2 + 0) << 7) + (c << 2)] = v;
    }
    if (p == (ju & 7)) {
      int mu = ju >> 3;
      float4 v = d[0];
      if (mu == 1) v = d[1]; else if (mu == 2) v = d[2];
      else if (mu == 3) v = d[3]; else if (mu == 4) v = d[4];
      *(float4*)&selw[(((b*NE_ + k)*2 + 1) << 7) + (c << 2)] = v;
    }
  }
}

// ============================================================================
// BN statistics: two-stage deterministic f64 reduction
// ============================================================================
__global__ __launch_bounds__(256) void k_bn1(const float* __restrict__ sumE,
                                             const float* __restrict__ sumSq,
                                             double* __restrict__ part)
{
  int g = blockIdx.x;                 // 0..255, rows [g*47, g*47+47)
  int t = threadIdx.x;
  int o = t & 127, h = t >> 7;
  int lo = g*47;
  int hi = lo + 47; if (hi > BR_) hi = BR_;
  double a1 = 0.0, a2 = 0.0;
  for (int i = lo + h; i < hi; i += 2) {
    a1 += (double)sumE [i*128 + o];
    a2 += (double)sumSq[i*128 + o];
  }
  __shared__ double sh1[256], sh2[256];
  sh1[t] = a1; sh2[t] = a2;
  __syncthreads();
  if (h == 0) {
    part[g*128 + o]           = sh1[o] + sh1[128 + o];
    part[256*128 + g*128 + o] = sh2[o] + sh2[128 + o];
  }
}

__global__ __launch_bounds__(128) void k_bn2(const double* __restrict__ part,
                                             const float* __restrict__ gamma,
                                             const float* __restrict__ beta,
                                             float* __restrict__ bnsc,
                                             float* __restrict__ bnsh)
{
  int o = threadIdx.x;
  double s1 = 0.0, s2 = 0.0;
  for (int g = 0; g < 256; ++g) {
    s1 += part[g*128 + o];
    s2 += part[256*128 + g*128 + o];
  }
  double cnt = (double)BR_ * 38.0;
  double m   = s1 / cnt;
  double var = s2 / cnt - m*m;
  double rs  = 1.0 / sqrt(var + 1e-5);
  double sc  = (double)gamma[o] * rs;
  bnsc[o] = (float)sc;
  bnsh[o] = beta[o] - (float)(m * sc);
}

// ============================================================================
// Kernel D: node discretization. Round-10: weights via w1t_n[l][k][o] — the
// 4 b32 loads per k-group are coalesced (lanes contiguous) instead of one
// b128 spanning 64 cache lines.
// ============================================================================
__global__ __launch_bounds__(128) void k_node(
    const float* __restrict__ sumE, const float* __restrict__ bnsc,
    const float* __restrict__ bnsh,
    const float* __restrict__ w1t_n, const float* __restrict__ b1,
    const float* __restrict__ w2, const float* __restrict__ b2,
    const float* __restrict__ x_deq, float* __restrict__ out)
{
  int blk = blockIdx.x;               // b*N + n
  int b   = blk / N_;
  int o   = threadIdx.x;
  __shared__ __align__(16) float xv[128];
  __shared__ __align__(16) float hb[128];
  __shared__ float lg[NT_];
  __shared__ int   P_s;
  int br = b*R_ + (blk - b*N_);       // r = n  (node replicas)
  xv[o] = sumE[br*128 + o]*bnsc[o] + 38.f*bnsh[o];
  if (o == 0) P_s = 0;
  __syncthreads();
  for (int l = 0; l < L_; ++l) {
    const float* wb = &w1t_n[(l << 14)];      // l*128*128
    float s = b1[l*128 + o];
    #pragma unroll 2
    for (int k = 0; k < 128; k += 4) {
      float4 x4 = *(const float4*)&xv[k];     // LDS broadcast
      s += wb[((k+0) << 7) + o]*x4.x + wb[((k+1) << 7) + o]*x4.y
         + wb[((k+2) << 7) + o]*x4.z + wb[((k+3) << 7) + o]*x4.w;
    }
    hb[o] = tanhf(s);
    __syncthreads();
    if (o < NT_) {
      const float* w2r = &w2[(l*NT_ + o)*128];
      float s2 = b2[l*NT_ + o];
      for (int k = 0; k < 128; ++k) s2 += w2r[k]*hb[k];
      lg[o] = s2;
    }
    __syncthreads();
    if (o == 0) {
      int best = 0; float bv = lg[0];
      #pragma unroll
      for (int cc = 1; cc < NT_; ++cc) if (lg[cc] > bv) { bv = lg[cc]; best = cc; }
      P_s += best;
    }
    __syncthreads();
  }
  int P = P_s % NT_;
  if (o < NT_) {
    int srcc = o - P; if (srcc < 0) srcc += NT_;
    out[blk*NT_ + o] = x_deq[blk*NT_ + srcc];
  }
}

// ============================================================================
// Kernel E: edge discretization, round-10 rewrite.
// Thread (c = t&31, p = t>>5): owns o-cols {4c..4c+3} x batches {p, p+8}.
// Weights from w1t_e[l][kk][o]: per-lane float4, 32 c-lanes contiguous 512B
// (COALESCED; old layout spanned 64 lines/load). xv reads: 2 b128 broadcasts
// per kk-group (was 8) -> LDS/layer 9.2k -> 2.3k cyc. 32 fma/group -> VALU-
// bound. hb row stride 132 keeps the w2-stage conflict-free (round-3 fix).
// ============================================================================
__global__ __launch_bounds__(256) void k_edge(
    const float* __restrict__ sumE, const float* __restrict__ selw,
    const float* __restrict__ bnsc, const float* __restrict__ bnsh,
    const float* __restrict__ w1t_e, const float* __restrict__ b1,
    const float* __restrict__ w2, const float* __restrict__ b2,
    const float* __restrict__ adj_deq, float* __restrict__ out)
{
  int k = blockIdx.x;                 // edge index 0..NE-1
  int t = threadIdx.x;
  int c = t & 31, p = t >> 5;
  __shared__ __align__(16) float xv[16][384];
  __shared__ __align__(16) float hb[16][132];
  __shared__ float lg[16][4];
  __shared__ int   Pf[16];

  for (int idx = t; idx < 16*128; idx += 256) {
    int b = idx >> 7, oo = idx & 127;
    float sc = bnsc[oo], sh = bnsh[oo];
    int base = ((b*NE_ + k)*2)*128;
    xv[b][oo]       = selw[base + oo]      *sc + sh;
    xv[b][128 + oo] = selw[base + 128 + oo]*sc + sh;
    xv[b][256 + oo] = sumE[(b*R_ + N_ + k)*128 + oo]*sc + 38.f*sh;
  }
  int Preg = 0;
  __syncthreads();

  for (int l = 0; l < L_; ++l) {
    float4 acc0, acc1;
    {
      float4 bb4 = *(const float4*)&b1[(l << 7) + (c << 2)];  // per-lane b128
      acc0 = bb4; acc1 = bb4;
    }
    const float* wl = &w1t_e[(l*384) << 7];
    #pragma unroll 2
    for (int kk = 0; kk < 384; kk += 4) {
      float4 x0 = *(const float4*)&xv[p][kk];       // b128 broadcast
      float4 x1 = *(const float4*)&xv[p + 8][kk];   // b128 broadcast
      const float* wk = wl + (kk << 7) + (c << 2);
      float4 w0 = *(const float4*)&wk[  0];         // coalesced 512B
      float4 w1 = *(const float4*)&wk[128];
      float4 w2v= *(const float4*)&wk[256];
      float4 w3 = *(const float4*)&wk[384];
      fma4(acc0, x0.x, w0); fma4(acc0, x0.y, w1); fma4(acc0, x0.z, w2v); fma4(acc0, x0.w, w3);
      fma4(acc1, x1.x, w0); fma4(acc1, x1.y, w1); fma4(acc1, x1.z, w2v); fma4(acc1, x1.w, w3);
    }
    {
      float4 h;
      h.x = tanhf(acc0.x); h.y = tanhf(acc0.y); h.z = tanhf(acc0.z); h.w = tanhf(acc0.w);
      *(float4*)&hb[p][c << 2] = h;
      h.x = tanhf(acc1.x); h.y = tanhf(acc1.y); h.z = tanhf(acc1.z); h.w = tanhf(acc1.w);
      *(float4*)&hb[p + 8][c << 2] = h;
    }
    __syncthreads();
    if (t < 64) {
      int m = t >> 2, c2 = t & 3;
      const float* w2r = &w2[(l*ET_ + c2)*128];
      float s2 = b2[l*ET_ + c2];
      for (int kk = 0; kk < 128; ++kk) s2 += w2r[kk]*hb[m][kk];
      lg[m][c2] = s2;
    }
    __syncthreads();
    if (t < 16) {
      int best = 0; float bv = lg[t][0];
      #pragma unroll
      for (int cc = 1; cc < ET_; ++cc) if (lg[t][cc] > bv) { bv = lg[t][cc]; best = cc; }
      Preg += best;
    }
    __syncthreads();
  }
  if (t < 16) Pf[t] = Preg & 3;       // mod 4
  __syncthreads();
  if (t < 64) {
    int m = t >> 2, c2 = t & 3;
    int srcc = c2 - Pf[m]; if (srcc < 0) srcc += ET_;
    out[(m*NE_ + k)*ET_ + c2] = adj_deq[(m*NE_ + k)*ET_ + srcc];
  }
}

// ============================================================================
extern "C" void kernel_launch(void* const* d_in, const int* in_sizes, int n_in,
                              void* d_out, int out_size, void* d_ws, size_t ws_size,
                              hipStream_t stream)
{
  (void)in_sizes; (void)n_in; (void)out_size; (void)ws_size;

  const float* x         = (const float*)d_in[0];
  const float* adj       = (const float*)d_in[1];
  const float* x_deq     = (const float*)d_in[2];
  const float* adj_deq   = (const float*)d_in[3];
  const int*   mask_node = (const int*)d_in[4];
  const int*   mask_edge = (const int*)d_in[5];
  const int*   isel      = (const int*)d_in[6];
  const float* emb_w     = (const float*)d_in[7];
  const float* gc1_w     = (const float*)d_in[8];
  const float* gc2_w     = (const float*)d_in[9];
  const float* gc3_w     = (const float*)d_in[10];
  const float* bn_gamma  = (const float*)d_in[11];
  const float* bn_beta   = (const float*)d_in[12];
  const float* node_w1   = (const float*)d_in[13];
  const float* node_b1   = (const float*)d_in[14];
  const float* node_w2   = (const float*)d_in[15];
  const float* node_b2   = (const float*)d_in[16];
  const float* edge_w1   = (const float*)d_in[17];
  const float* edge_b1   = (const float*)d_in[18];
  const float* edge_w2   = (const float*)d_in[19];
  const float* edge_b2   = (const float*)d_in[20];

  float* out_f = (float*)d_out;

  // Workspace layout (~25 MB). Two overlays, both safe by stream order:
  //  - Wt (393 KB) overlays `part` (524 KB): Wt consumed by k_rgcn, which
  //    completes before k_bn1 writes part.
  //  - w1t_e/w1t_n (786432 floats) overlay sumSq (1517568 floats): sumSq is
  //    dead after k_bn1; k_wt2 launches after k_bn1.
  float*  wsf   = (float*)d_ws;
  float*  sx    = wsf;                      // 608*384       = 233472
  float*  sumE  = sx    + 233472;           // 11856*128     = 1517568
  float*  sumSq = sumE  + 1517568;          // 1517568
  float*  selw  = sumSq + 1517568;          // 16*703*2*128  = 2879488
  float*  bnsc  = selw  + 2879488;          // 128
  float*  bnsh  = bnsc  + 128;              // 128
  double* part  = (double*)(bnsh + 128);    // 2*256*128 doubles
  float*  Wt    = (float*)part;             // 98304 floats (overlay #1)
  float*  w1t_e = sumSq;                    // 589824 floats (overlay #2)
  float*  w1t_n = sumSq + 589824;           // 196608 floats

  k_wt  <<<768,      128, 0, stream>>>(gc2_w, gc3_w, Wt);
  k_sx  <<<B_*N_,    128, 0, stream>>>(x, emb_w, gc1_w, sx);
  k_rgcn<<<BR_,      256, 0, stream>>>(adj, mask_node, mask_edge, isel, sx,
                                       Wt, sumE, sumSq, selw);
  k_bn1 <<<256,      256, 0, stream>>>(sumE, sumSq, part);
  k_bn2 <<<1,        128, 0, stream>>>(part, bn_gamma, bn_beta, bnsc, bnsh);
  k_wt2 <<<12*384 + 12*128, 128, 0, stream>>>(node_w1, edge_w1, w1t_e, w1t_n);
  k_node<<<B_*N_,    128, 0, stream>>>(sumE, bnsc, bnsh, w1t_n, node_b1,
                                       node_w2, node_b2, x_deq, out_f);
  k_edge<<<NE_,      256, 0, stream>>>(sumE, selw, bnsc, bnsh, w1t_e, edge_b1,
                                       edge_w2, edge_b2, adj_deq,
                                       out_f + B_*N_*NT_);
}

// Round 11
// 2077.357 us; speedup vs baseline: 1.2015x; 1.0633x over previous
//
#include <hip/hip_runtime.h>

#define B_   16
#define N_   38
#define NT_  9
#define ET_  4
#define NE_  703
#define R_   741
#define L_   12
#define BR_  11856   // B_*R_

// ============================================================================
// Kernel A: sx[b,n,eo] = ((x @ emb_w^T) @ gc1_w^T)[b,n,eo]   (B*N blocks)
// ============================================================================
__global__ __launch_bounds__(128) void k_sx(const float* __restrict__ x,
                                            const float* __restrict__ emb_w,
                                            const float* __restrict__ gc1_w,
                                            float* __restrict__ sx)
{
  int bn = blockIdx.x;            // b*N + n
  int t  = threadIdx.x;
  __shared__ float xr[NT_];
  __shared__ float hx[NT_];
  if (t < NT_) xr[t] = x[bn*NT_ + t];
  __syncthreads();
  if (t < NT_) {
    float s = 0.f;
    #pragma unroll
    for (int u = 0; u < NT_; ++u) s += xr[u] * emb_w[t*NT_ + u];
    hx[t] = s;
  }
  __syncthreads();
  for (int eo = t; eo < 384; eo += 128) {
    float s = 0.f;
    #pragma unroll
    for (int u = 0; u < NT_; ++u) s += hx[u] * gc1_w[eo*NT_ + u];
    sx[bn*384 + eo] = s;
  }
}

// ============================================================================
// Kernel A2: transpose gc2_w/gc3_w into Wt[(which*3+e)*128 + k][o]  (coalesced)
// ============================================================================
__global__ __launch_bounds__(128) void k_wt(const float* __restrict__ gc2_w,
                                            const float* __restrict__ gc3_w,
                                            float* __restrict__ Wt)
{
  int blk   = blockIdx.x;
  int which = blk / 384;
  int rem   = blk - which*384;
  int e     = rem >> 7;
  int k     = rem & 127;
  int o     = threadIdx.x;
  const float* src = which ? gc3_w : gc2_w;
  Wt[(((which*3 + e) << 7) + k)*128 + o] = src[((e << 7) + o)*128 + k];
}

// ============================================================================
// Kernel A3: transpose node_w1/edge_w1 to [l][k][o] (coalesced; round-10 fix).
// ============================================================================
__global__ __launch_bounds__(128) void k_wt2(const float* __restrict__ node_w1,
                                             const float* __restrict__ edge_w1,
                                             float* __restrict__ w1t_e,
                                             float* __restrict__ w1t_n)
{
  int blk = blockIdx.x;
  int o   = threadIdx.x;
  if (blk < 12*384) {
    int l = blk / 384, kk = blk - l*384;
    w1t_e[blk*128 + o] = edge_w1[(l*128 + o)*384 + kk];
  } else {
    int row = blk - 12*384;               // l*128 + k
    int l = row >> 7, k = row & 127;
    w1t_n[row*128 + o] = node_w1[(l*128 + o)*128 + k];
  }
}

// ============================================================================
// Kernel B: per-(b,r) RGCN, 256 threads.  (round-9 version, unchanged: 1.71ms,
// VALUBusy 76%, occ 45%, no spill — ~15% above the 0.86ms fma floor.)
// ============================================================================
__device__ __forceinline__ void fma4(float4& d, float a, const float4& s) {
  d.x += a*s.x; d.y += a*s.y; d.z += a*s.z; d.w += a*s.w;
}

__device__ __forceinline__ void ldA(const float* __restrict__ adj,
                                    const int* __restrict__ mask_edge,
                                    int b, int r, int e, int tid,
                                    float av[5], float a1v[2])
{
  #pragma unroll
  for (int t = 0; t < 5; ++t) {
    int m = tid + (t << 8);
    float v = 0.f;
    if (m < 1216) {
      int j = m >> 5, slot = m & 31;
      int i = (slot >> 2) + ((slot & 3) << 3);          // < 38
      int   msk = mask_edge[(r*N_ + i)*N_ + j];
      float a   = adj[((b*ET_ + e)*N_ + i)*N_ + j];     // unconditional
      v = msk ? a : 0.f;
    }
    av[t] = v;
  }
  #pragma unroll
  for (int t = 0; t < 2; ++t) {
    int m = tid + (t << 8);
    float v = 0.f;
    if (m < 304) {
      int j = m >> 3;
      int i = (m & 7) + 32;                             // 32..39
      if (i < N_) {
        int   msk = mask_edge[(r*N_ + i)*N_ + j];
        float a   = adj[((b*ET_ + e)*N_ + i)*N_ + j];
        v = msk ? a : 0.f;
      }
    }
    a1v[t] = v;
  }
}

__device__ __forceinline__ void stA(float* __restrict__ A4e,
                                    float* __restrict__ A1e, int tid,
                                    const float av[5], const float a1v[2])
{
  #pragma unroll
  for (int t = 0; t < 5; ++t) {
    int m = tid + (t << 8);
    if (m < 1216) A4e[m] = av[t];
  }
  #pragma unroll
  for (int t = 0; t < 2; ++t) {
    int m = tid + (t << 8);
    if (m < 304) A1e[m] = a1v[t];
  }
}

__device__ __forceinline__ void eacc_m(const float* __restrict__ A4e,
                                       const float* __restrict__ A1e,
                                       const float* __restrict__ S_l,
                                       int p, int c,
                                       const int* __restrict__ mn,
                                       float4 d[5])
{
  #pragma unroll 2
  for (int j = 0; j < 38; ++j) {
    if (!mn[j]) continue;                             // uniform branch
    float4 s4 = *(const float4*)&S_l[(j << 7) + (c << 2)];
    float4 a4 = *(const float4*)&A4e[(j << 5) + (p << 2)];
    float  a1 = A1e[(j << 3) + p];
    fma4(d[0], a4.x, s4); fma4(d[1], a4.y, s4); fma4(d[2], a4.z, s4);
    fma4(d[3], a4.w, s4); fma4(d[4], a1,   s4);
  }
}

__device__ __forceinline__ void eacc_u(const float* __restrict__ A4e,
                                       const float* __restrict__ A1e,
                                       const float* __restrict__ S_l,
                                       int p, int c,
                                       float4 d[5])
{
  #pragma unroll 4
  for (int j = 0; j < 38; ++j) {
    float4 s4 = *(const float4*)&S_l[(j << 7) + (c << 2)];
    float4 a4 = *(const float4*)&A4e[(j << 5) + (p << 2)];
    float  a1 = A1e[(j << 3) + p];
    fma4(d[0], a4.x, s4); fma4(d[1], a4.y, s4); fma4(d[2], a4.z, s4);
    fma4(d[3], a4.w, s4); fma4(d[4], a1,   s4);
  }
}

__device__ __forceinline__ void gemm_fused(const float* __restrict__ H_l,
                                           const float* __restrict__ Wb,
                                           int p, int c, float4 g[3][5])
{
  #pragma unroll
  for (int e = 0; e < 3; ++e)
    #pragma unroll
    for (int q = 0; q < 5; ++q) { g[e][q].x = 0.f; g[e][q].y = 0.f; g[e][q].z = 0.f; g[e][q].w = 0.f; }
  #pragma unroll 1
  for (int k0 = 0; k0 < 128; k0 += 4) {
    float4 h0 = *(const float4*)&H_l[((p+ 0) << 7) + k0];
    float4 h1 = *(const float4*)&H_l[((p+ 8) << 7) + k0];
    float4 h2 = *(const float4*)&H_l[((p+16) << 7) + k0];
    float4 h3 = *(const float4*)&H_l[((p+24) << 7) + k0];
    float4 h4 = *(const float4*)&H_l[((p+32) << 7) + k0];
    #pragma unroll
    for (int e = 0; e < 3; ++e) {
      const float* We = &Wb[(e << 14) + (k0 << 7) + (c << 2)];
      float4 w0 = *(const float4*)&We[  0];
      float4 w1 = *(const float4*)&We[128];
      float4 w2 = *(const float4*)&We[256];
      float4 w3 = *(const float4*)&We[384];
      fma4(g[e][0], h0.x, w0); fma4(g[e][0], h0.y, w1); fma4(g[e][0], h0.z, w2); fma4(g[e][0], h0.w, w3);
      fma4(g[e][1], h1.x, w0); fma4(g[e][1], h1.y, w1); fma4(g[e][1], h1.z, w2); fma4(g[e][1], h1.w, w3);
      fma4(g[e][2], h2.x, w0); fma4(g[e][2], h2.y, w1); fma4(g[e][2], h2.z, w2); fma4(g[e][2], h2.w, w3);
      fma4(g[e][3], h3.x, w0); fma4(g[e][3], h3.y, w1); fma4(g[e][3], h3.z, w2); fma4(g[e][3], h3.w, w3);
      fma4(g[e][4], h4.x, w0); fma4(g[e][4], h4.y, w1); fma4(g[e][4], h4.z, w2); fma4(g[e][4], h4.w, w3);
    }
  }
}

__device__ __forceinline__ void relu_store(float* __restrict__ H_l, int p, int c,
                                           const float4 d[5])
{
  #pragma unroll
  for (int q = 0; q < 5; ++q) {
    float4 t;
    t.x = fmaxf(d[q].x, 0.f); t.y = fmaxf(d[q].y, 0.f);
    t.z = fmaxf(d[q].z, 0.f); t.w = fmaxf(d[q].w, 0.f);
    *(float4*)&H_l[((p + (q << 3)) << 7) + (c << 2)] = t;
  }
}

__global__ __launch_bounds__(256) void k_rgcn(
    const float* __restrict__ adj, const int* __restrict__ mask_node,
    const int* __restrict__ mask_edge, const int* __restrict__ isel,
    const float* __restrict__ sx, const float* __restrict__ Wt,
    float* __restrict__ sumE, float* __restrict__ sumSq,
    float* __restrict__ selw)
{
  const int br  = blockIdx.x;
  const int b   = br / R_;
  const int r   = br - b*R_;
  const int tid = threadIdx.x;
  const int c   = tid & 31;
  const int p   = tid >> 5;

  __shared__ __align__(16) float A4_l[3*1216];   // 14592 B (all 3 e, resident)
  __shared__ __align__(16) float A1_l[3*304];    //  3648 B
  __shared__ __align__(16) float SH_l[40*128];   // 20480 B (S and H, time-shared)
  __shared__ int mn_l[40];

  if (tid < 40) mn_l[tid] = (tid < 38) ? mask_node[r*N_ + tid] : 0;

  float av[5], a1v[2];
  ldA(adj, mask_edge, b, r, 0, tid, av, a1v);    // prefetch e=0
  __syncthreads();                               // mn_l visible

  float4 d[5];
  #pragma unroll
  for (int q = 0; q < 5; ++q) { d[q].x = d[q].y = d[q].z = d[q].w = 0.f; }

  // ---------------- gconv 1: S-fill + A-fill(once) + einsum, pipelined ------
  for (int e = 0; e < 3; ++e) {
    for (int idx = tid; idx < 40*32; idx += 256) {
      int j = idx >> 5, q4 = idx & 31;
      float4 v; v.x = v.y = v.z = v.w = 0.f;
      if (j < N_ && mn_l[j]) v = *(const float4*)&sx[(b*N_ + j)*384 + (e << 7) + (q4 << 2)];
      *(float4*)&SH_l[(j << 7) + (q4 << 2)] = v;
    }
    stA(&A4_l[e*1216], &A1_l[e*304], tid, av, a1v);
    __syncthreads();
    if (e < 2) ldA(adj, mask_edge, b, r, e+1, tid, av, a1v);  // hide under eacc
    eacc_m(&A4_l[e*1216], &A1_l[e*304], SH_l, p, c, mn_l, d);
    __syncthreads();                       // einsum done before S refill
  }
  relu_store(SH_l, p, c, d);               // SH now holds H (all 40 rows)
  __syncthreads();

  // ---------------- gconv 2 (gv=0) and gconv 3 (gv=1), fused-e gemm ---------
  for (int gv = 0; gv < 2; ++gv) {
    float4 g[3][5];
    gemm_fused(SH_l, &Wt[gv*49152], p, c, g);   // consumes ALL of H into regs
    #pragma unroll
    for (int q = 0; q < 5; ++q) { d[q].x = d[q].y = d[q].z = d[q].w = 0.f; }
    #pragma unroll
    for (int e = 0; e < 3; ++e) {
      __syncthreads();      // e=0: gemm H-reads done; e>0: prior eacc S-reads done
      #pragma unroll
      for (int q = 0; q < 5; ++q)
        *(float4*)&SH_l[((p + (q << 3)) << 7) + (c << 2)] = g[e][q];
      __syncthreads();
      eacc_u(&A4_l[e*1216], &A1_l[e*304], SH_l, p, c, d);
    }
    if (gv == 0) {
      __syncthreads();      // eacc (e=2) readers of SH done before H overwrite
      relu_store(SH_l, p, c, d);
      __syncthreads();      // H visible before gv=1 gemm reads it
    }
  }
  __syncthreads();   // last einsum done before SH reuse below

  // ---------------- BN partials + edge node selection ----------------
  {
    float4 sA, sB;
    sA.x = d[0].x+d[1].x+d[2].x+d[3].x+d[4].x;
    sA.y = d[0].y+d[1].y+d[2].y+d[3].y+d[4].y;
    sA.z = d[0].z+d[1].z+d[2].z+d[3].z+d[4].z;
    sA.w = d[0].w+d[1].w+d[2].w+d[3].w+d[4].w;
    sB.x = d[0].x*d[0].x+d[1].x*d[1].x+d[2].x*d[2].x+d[3].x*d[3].x+d[4].x*d[4].x;
    sB.y = d[0].y*d[0].y+d[1].y*d[1].y+d[2].y*d[2].y+d[3].y*d[3].y+d[4].y*d[4].y;
    sB.z = d[0].z*d[0].z+d[1].z*d[1].z+d[2].z*d[2].z+d[3].z*d[3].z+d[4].z*d[4].z;
    sB.w = d[0].w*d[0].w+d[1].w*d[1].w+d[2].w*d[2].w+d[3].w*d[3].w+d[4].w*d[4].w;
    *(float4*)&SH_l[( p      << 7) + (c << 2)] = sA;   // rows 0..7  : sums
    *(float4*)&SH_l[((8 + p) << 7) + (c << 2)] = sB;   // rows 8..15 : squares
  }
  __syncthreads();
  {
    int o = tid & 127, half = tid >> 7;
    float t = 0.f;
    #pragma unroll
    for (int pp = 0; pp < 8; ++pp) t += SH_l[(((half << 3) + pp) << 7) + o];
    if (half == 0) sumE [br*128 + o] = t;
    else           sumSq[br*128 + o] = t;
  }
  if (r >= N_) {
    int k  = r - N_;
    int iu = isel[2*k], ju = isel[2*k+1];
    if (p == (iu & 7)) {
      int mu = iu >> 3;
      float4 v = d[0];
      if (mu == 1) v = d[1]; else if (mu == 2) v = d[2];
      else if (mu == 3) v = d[3]; else if (mu == 4) v = d[4];
      *(float4*)&selw[(((b*NE_ + k)*2 + 0) << 7) + (c << 2)] = v;
    }
    if (p == (ju & 7)) {
      int mu = ju >> 3;
      float4 v = d[0];
      if (mu == 1) v = d[1]; else if (mu == 2) v = d[2];
      else if (mu == 3) v = d[3]; else if (mu == 4) v = d[4];
      *(float4*)&selw[(((b*NE_ + k)*2 + 1) << 7) + (c << 2)] = v;
    }
  }
}

// ============================================================================
// Kernel Z: zero the argmax-shift accumulators (ws is re-poisoned 0xAA).
// ============================================================================
__global__ __launch_bounds__(256) void k_zero(int* __restrict__ Pn,
                                              int* __restrict__ Pe)
{
  int i = blockIdx.x*256 + threadIdx.x;
  if (i < B_*N_)   Pn[i] = 0;
  if (i < B_*NE_)  Pe[i] = 0;
}

// ============================================================================
// BN statistics: two-stage deterministic f64 reduction
// ============================================================================
__global__ __launch_bounds__(256) void k_bn1(const float* __restrict__ sumE,
                                             const float* __restrict__ sumSq,
                                             double* __restrict__ part)
{
  int g = blockIdx.x;                 // 0..255, rows [g*47, g*47+47)
  int t = threadIdx.x;
  int o = t & 127, h = t >> 7;
  int lo = g*47;
  int hi = lo + 47; if (hi > BR_) hi = BR_;
  double a1 = 0.0, a2 = 0.0;
  for (int i = lo + h; i < hi; i += 2) {
    a1 += (double)sumE [i*128 + o];
    a2 += (double)sumSq[i*128 + o];
  }
  __shared__ double sh1[256], sh2[256];
  sh1[t] = a1; sh2[t] = a2;
  __syncthreads();
  if (h == 0) {
    part[g*128 + o]           = sh1[o] + sh1[128 + o];
    part[256*128 + g*128 + o] = sh2[o] + sh2[128 + o];
  }
}

__global__ __launch_bounds__(128) void k_bn2(const double* __restrict__ part,
                                             const float* __restrict__ gamma,
                                             const float* __restrict__ beta,
                                             float* __restrict__ bnsc,
                                             float* __restrict__ bnsh)
{
  int o = threadIdx.x;
  double s1 = 0.0, s2 = 0.0;
  for (int g = 0; g < 256; ++g) {
    s1 += part[g*128 + o];
    s2 += part[256*128 + g*128 + o];
  }
  double cnt = (double)BR_ * 38.0;
  double m   = s1 / cnt;
  double var = s2 / cnt - m*m;
  double rs  = 1.0 / sqrt(var + 1e-5);
  double sc  = (double)gamma[o] * rs;
  bnsc[o] = (float)sc;
  bnsh[o] = beta[o] - (float)(m * sc);
}

// ============================================================================
// Kernel D (round-11): node discretization, LAYER-PARALLEL.
// xv is loop-invariant and only Σ argmax crosses layers -> each block does
// ONE (bn, l) pair; integer atomicAdd of the argmax (order-independent ->
// deterministic). Grid 608 -> 7296 blocks: kills the serial 12-stage chain.
// ============================================================================
__global__ __launch_bounds__(128) void k_node_par(
    const float* __restrict__ sumE, const float* __restrict__ bnsc,
    const float* __restrict__ bnsh,
    const float* __restrict__ w1t_n, const float* __restrict__ b1,
    const float* __restrict__ w2, const float* __restrict__ b2,
    int* __restrict__ Pn)
{
  int blk = blockIdx.x;               // l*608 + bn
  int l   = blk / (B_*N_);
  int bn  = blk - l*(B_*N_);
  int b   = bn / N_;
  int o   = threadIdx.x;
  __shared__ __align__(16) float xv[128];
  __shared__ __align__(16) float hb[128];
  __shared__ float lg[NT_];
  int br = b*R_ + (bn - b*N_);        // r = n
  xv[o] = sumE[br*128 + o]*bnsc[o] + 38.f*bnsh[o];
  __syncthreads();
  const float* wb = &w1t_n[l << 14];
  float s = b1[l*128 + o];
  #pragma unroll 2
  for (int k = 0; k < 128; k += 4) {
    float4 x4 = *(const float4*)&xv[k];       // LDS broadcast
    s += wb[((k+0) << 7) + o]*x4.x + wb[((k+1) << 7) + o]*x4.y
       + wb[((k+2) << 7) + o]*x4.z + wb[((k+3) << 7) + o]*x4.w;
  }
  hb[o] = tanhf(s);
  __syncthreads();
  if (o < NT_) {
    const float* w2r = &w2[(l*NT_ + o)*128];
    float s2 = b2[l*NT_ + o];
    for (int k = 0; k < 128; ++k) s2 += w2r[k]*hb[k];
    lg[o] = s2;
  }
  __syncthreads();
  if (o == 0) {
    int best = 0; float bv = lg[0];
    #pragma unroll
    for (int cc = 1; cc < NT_; ++cc) if (lg[cc] > bv) { bv = lg[cc]; best = cc; }
    atomicAdd(&Pn[bn], best);
  }
}

// ============================================================================
// Kernel E (round-11): edge discretization, LAYER-PARALLEL. One block per
// (l, k): all 16 batches; argmax per batch -> atomicAdd into Pe[b*NE+k].
// Grid 703 -> 8436 blocks (33/CU). Coalesced w1t_e (round-10), hb stride 132
// (round-3 conflict fix). Per block: ~3 barriers instead of ~36.
// ============================================================================
__global__ __launch_bounds__(256) void k_edge_par(
    const float* __restrict__ sumE, const float* __restrict__ selw,
    const float* __restrict__ bnsc, const float* __restrict__ bnsh,
    const float* __restrict__ w1t_e, const float* __restrict__ b1,
    const float* __restrict__ w2, const float* __restrict__ b2,
    int* __restrict__ Pe)
{
  int blk = blockIdx.x;               // l*NE + k
  int l = blk / NE_;
  int k = blk - l*NE_;
  int t = threadIdx.x;
  int c = t & 31, p = t >> 5;
  __shared__ __align__(16) float xv[16][384];
  __shared__ __align__(16) float hb[16][132];
  __shared__ float lg[16][4];

  for (int idx = t; idx < 16*128; idx += 256) {
    int b = idx >> 7, oo = idx & 127;
    float sc = bnsc[oo], sh = bnsh[oo];
    int base = ((b*NE_ + k)*2)*128;
    xv[b][oo]       = selw[base + oo]      *sc + sh;
    xv[b][128 + oo] = selw[base + 128 + oo]*sc + sh;
    xv[b][256 + oo] = sumE[(b*R_ + N_ + k)*128 + oo]*sc + 38.f*sh;
  }
  __syncthreads();

  float4 acc0, acc1;
  {
    float4 bb4 = *(const float4*)&b1[(l << 7) + (c << 2)];
    acc0 = bb4; acc1 = bb4;
  }
  const float* wl = &w1t_e[(l*384) << 7];
  #pragma unroll 2
  for (int kk = 0; kk < 384; kk += 4) {
    float4 x0 = *(const float4*)&xv[p][kk];       // b128 broadcast
    float4 x1 = *(const float4*)&xv[p + 8][kk];   // b128 broadcast
    const float* wk = wl + (kk << 7) + (c << 2);
    float4 w0 = *(const float4*)&wk[  0];         // coalesced 512B
    float4 w1 = *(const float4*)&wk[128];
    float4 w2v= *(const float4*)&wk[256];
    float4 w3 = *(const float4*)&wk[384];
    fma4(acc0, x0.x, w0); fma4(acc0, x0.y, w1); fma4(acc0, x0.z, w2v); fma4(acc0, x0.w, w3);
    fma4(acc1, x1.x, w0); fma4(acc1, x1.y, w1); fma4(acc1, x1.z, w2v); fma4(acc1, x1.w, w3);
  }
  {
    float4 h;
    h.x = tanhf(acc0.x); h.y = tanhf(acc0.y); h.z = tanhf(acc0.z); h.w = tanhf(acc0.w);
    *(float4*)&hb[p][c << 2] = h;
    h.x = tanhf(acc1.x); h.y = tanhf(acc1.y); h.z = tanhf(acc1.z); h.w = tanhf(acc1.w);
    *(float4*)&hb[p + 8][c << 2] = h;
  }
  __syncthreads();
  if (t < 64) {
    int m = t >> 2, c2 = t & 3;
    const float* w2r = &w2[(l*ET_ + c2)*128];
    float s2 = b2[l*ET_ + c2];
    for (int kk = 0; kk < 128; ++kk) s2 += w2r[kk]*hb[m][kk];
    lg[m][c2] = s2;
  }
  __syncthreads();
  if (t < 16) {
    int best = 0; float bv = lg[t][0];
    #pragma unroll
    for (int cc = 1; cc < ET_; ++cc) if (lg[t][cc] > bv) { bv = lg[t][cc]; best = cc; }
    atomicAdd(&Pe[t*NE_ + k], best);
  }
}

// ============================================================================
// Kernel G: apply the accumulated circular shifts (node then edge blocks).
// ============================================================================
__global__ __launch_bounds__(64) void k_gather(
    const int* __restrict__ Pn, const int* __restrict__ Pe,
    const float* __restrict__ x_deq, const float* __restrict__ adj_deq,
    float* __restrict__ out)
{
  int blk = blockIdx.x;
  int t   = threadIdx.x;
  if (blk < B_*N_) {
    if (t < NT_) {
      int P = Pn[blk] % NT_;
      int src = t - P; if (src < 0) src += NT_;
      out[blk*NT_ + t] = x_deq[blk*NT_ + src];
    }
  } else {
    int k = blk - B_*N_;
    int m = t >> 2, c2 = t & 3;
    int P = Pe[m*NE_ + k] & 3;
    int src = c2 - P; if (src < 0) src += ET_;
    out[B_*N_*NT_ + (m*NE_ + k)*ET_ + c2] = adj_deq[(m*NE_ + k)*ET_ + src];
  }
}

// ============================================================================
extern "C" void kernel_launch(void* const* d_in, const int* in_sizes, int n_in,
                              void* d_out, int out_size, void* d_ws, size_t ws_size,
                              hipStream_t stream)
{
  (void)in_sizes; (void)n_in; (void)out_size; (void)ws_size;

  const float* x         = (const float*)d_in[0];
  const float* adj       = (const float*)d_in[1];
  const float* x_deq     = (const float*)d_in[2];
  const float* adj_deq   = (const float*)d_in[3];
  const int*   mask_node = (const int*)d_in[4];
  const int*   mask_edge = (const int*)d_in[5];
  const int*   isel      = (const int*)d_in[6];
  const float* emb_w     = (const float*)d_in[7];
  const float* gc1_w     = (const float*)d_in[8];
  const float* gc2_w     = (const float*)d_in[9];
  const float* gc3_w     = (const float*)d_in[10];
  const float* bn_gamma  = (const float*)d_in[11];
  const float* bn_beta   = (const float*)d_in[12];
  const float* node_w1   = (const float*)d_in[13];
  const float* node_b1   = (const float*)d_in[14];
  const float* node_w2   = (const float*)d_in[15];
  const float* node_b2   = (const float*)d_in[16];
  const float* edge_w1   = (const float*)d_in[17];
  const float* edge_b1   = (const float*)d_in[18];
  const float* edge_w2   = (const float*)d_in[19];
  const float* edge_b2   = (const float*)d_in[20];

  float* out_f = (float*)d_out;

  // Workspace layout (~25 MB). Three overlays, all safe by stream order:
  //  - Wt (393 KB) overlays `part` (524 KB): consumed by k_rgcn < k_bn1.
  //  - w1t_e/w1t_n overlay sumSq: dead after k_bn1; k_wt2 launches after.
  //  - Pn/Pe (ints) overlay sx: dead after k_rgcn; k_zero launches after.
  float*  wsf   = (float*)d_ws;
  float*  sx    = wsf;                      // 608*384       = 233472
  float*  sumE  = sx    + 233472;           // 11856*128     = 1517568
  float*  sumSq = sumE  + 1517568;          // 1517568
  float*  selw  = sumSq + 1517568;          // 16*703*2*128  = 2879488
  float*  bnsc  = selw  + 2879488;          // 128
  float*  bnsh  = bnsc  + 128;              // 128
  double* part  = (double*)(bnsh + 128);    // 2*256*128 doubles
  float*  Wt    = (float*)part;             // 98304 floats (overlay #1)
  float*  w1t_e = sumSq;                    // 589824 floats (overlay #2)
  float*  w1t_n = sumSq + 589824;           // 196608 floats
  int*    Pn    = (int*)sx;                 // 608 ints      (overlay #3)
  int*    Pe    = Pn + B_*N_;               // 11248 ints

  k_wt      <<<768,           128, 0, stream>>>(gc2_w, gc3_w, Wt);
  k_sx      <<<B_*N_,         128, 0, stream>>>(x, emb_w, gc1_w, sx);
  k_rgcn    <<<BR_,           256, 0, stream>>>(adj, mask_node, mask_edge, isel,
                                                sx, Wt, sumE, sumSq, selw);
  k_zero    <<<(B_*NE_ + 255)/256, 256, 0, stream>>>(Pn, Pe);
  k_bn1     <<<256,           256, 0, stream>>>(sumE, sumSq, part);
  k_bn2     <<<1,             128, 0, stream>>>(part, bn_gamma, bn_beta, bnsc, bnsh);
  k_wt2     <<<12*384+12*128, 128, 0, stream>>>(node_w1, edge_w1, w1t_e, w1t_n);
  k_node_par<<<L_*B_*N_,      128, 0, stream>>>(sumE, bnsc, bnsh, w1t_n, node_b1,
                                                node_w2, node_b2, Pn);
  k_edge_par<<<L_*NE_,        256, 0, stream>>>(sumE, selw, bnsc, bnsh, w1t_e,
                                                edge_b1, edge_w2, edge_b2, Pe);
  k_gather  <<<B_*N_ + NE_,    64, 0, stream>>>(Pn, Pe, x_deq, adj_deq, out_f);
}

// Round 12
// 2073.350 us; speedup vs baseline: 1.2038x; 1.0019x over previous
//
#include <hip/hip_runtime.h>

#define B_   16
#define N_   38
#define NT_  9
#define ET_  4
#define NE_  703
#define R_   741
#define L_   12
#define BR_  11856   // B_*R_

// ============================================================================
// Kernel A: sx[b,n,eo] = ((x @ emb_w^T) @ gc1_w^T)[b,n,eo]   (B*N blocks)
// ============================================================================
__global__ __launch_bounds__(128) void k_sx(const float* __restrict__ x,
                                            const float* __restrict__ emb_w,
                                            const float* __restrict__ gc1_w,
                                            float* __restrict__ sx)
{
  int bn = blockIdx.x;            // b*N + n
  int t  = threadIdx.x;
  __shared__ float xr[NT_];
  __shared__ float hx[NT_];
  if (t < NT_) xr[t] = x[bn*NT_ + t];
  __syncthreads();
  if (t < NT_) {
    float s = 0.f;
    #pragma unroll
    for (int u = 0; u < NT_; ++u) s += xr[u] * emb_w[t*NT_ + u];
    hx[t] = s;
  }
  __syncthreads();
  for (int eo = t; eo < 384; eo += 128) {
    float s = 0.f;
    #pragma unroll
    for (int u = 0; u < NT_; ++u) s += hx[u] * gc1_w[eo*NT_ + u];
    sx[bn*384 + eo] = s;
  }
}

// ============================================================================
// Kernel A2: transpose gc2_w/gc3_w into Wt[(which*3+e)*128 + k][o]  (coalesced)
// ============================================================================
__global__ __launch_bounds__(128) void k_wt(const float* __restrict__ gc2_w,
                                            const float* __restrict__ gc3_w,
                                            float* __restrict__ Wt)
{
  int blk   = blockIdx.x;
  int which = blk / 384;
  int rem   = blk - which*384;
  int e     = rem >> 7;
  int k     = rem & 127;
  int o     = threadIdx.x;
  const float* src = which ? gc3_w : gc2_w;
  Wt[(((which*3 + e) << 7) + k)*128 + o] = src[((e << 7) + o)*128 + k];
}

// ============================================================================
// Kernel A3: transpose node_w1/edge_w1 to [l][k][o] (coalesced; round-10 fix).
// ============================================================================
__global__ __launch_bounds__(128) void k_wt2(const float* __restrict__ node_w1,
                                             const float* __restrict__ edge_w1,
                                             float* __restrict__ w1t_e,
                                             float* __restrict__ w1t_n)
{
  int blk = blockIdx.x;
  int o   = threadIdx.x;
  if (blk < 12*384) {
    int l = blk / 384, kk = blk - l*384;
    w1t_e[blk*128 + o] = edge_w1[(l*128 + o)*384 + kk];
  } else {
    int row = blk - 12*384;               // l*128 + k
    int l = row >> 7, k = row & 127;
    w1t_n[row*128 + o] = node_w1[(l*128 + o)*128 + k];
  }
}

// ============================================================================
// Kernel B: per-(b,r) RGCN, 256 threads.  (round-9 version, FROZEN: 1.71ms,
// VALUBusy 76%, occ 45%, no spill. Residual vs 0.86ms fma floor is addressing
// VALU + barrier idle — structural to the LDS einsum; no fp32 MFMA exists.)
// ============================================================================
__device__ __forceinline__ void fma4(float4& d, float a, const float4& s) {
  d.x += a*s.x; d.y += a*s.y; d.z += a*s.z; d.w += a*s.w;
}

__device__ __forceinline__ void ldA(const float* __restrict__ adj,
                                    const int* __restrict__ mask_edge,
                                    int b, int r, int e, int tid,
                                    float av[5], float a1v[2])
{
  #pragma unroll
  for (int t = 0; t < 5; ++t) {
    int m = tid + (t << 8);
    float v = 0.f;
    if (m < 1216) {
      int j = m >> 5, slot = m & 31;
      int i = (slot >> 2) + ((slot & 3) << 3);          // < 38
      int   msk = mask_edge[(r*N_ + i)*N_ + j];
      float a   = adj[((b*ET_ + e)*N_ + i)*N_ + j];     // unconditional
      v = msk ? a : 0.f;
    }
    av[t] = v;
  }
  #pragma unroll
  for (int t = 0; t < 2; ++t) {
    int m = tid + (t << 8);
    float v = 0.f;
    if (m < 304) {
      int j = m >> 3;
      int i = (m & 7) + 32;                             // 32..39
      if (i < N_) {
        int   msk = mask_edge[(r*N_ + i)*N_ + j];
        float a   = adj[((b*ET_ + e)*N_ + i)*N_ + j];
        v = msk ? a : 0.f;
      }
    }
    a1v[t] = v;
  }
}

__device__ __forceinline__ void stA(float* __restrict__ A4e,
                                    float* __restrict__ A1e, int tid,
                                    const float av[5], const float a1v[2])
{
  #pragma unroll
  for (int t = 0; t < 5; ++t) {
    int m = tid + (t << 8);
    if (m < 1216) A4e[m] = av[t];
  }
  #pragma unroll
  for (int t = 0; t < 2; ++t) {
    int m = tid + (t << 8);
    if (m < 304) A1e[m] = a1v[t];
  }
}

__device__ __forceinline__ void eacc_m(const float* __restrict__ A4e,
                                       const float* __restrict__ A1e,
                                       const float* __restrict__ S_l,
                                       int p, int c,
                                       const int* __restrict__ mn,
                                       float4 d[5])
{
  #pragma unroll 2
  for (int j = 0; j < 38; ++j) {
    if (!mn[j]) continue;                             // uniform branch
    float4 s4 = *(const float4*)&S_l[(j << 7) + (c << 2)];
    float4 a4 = *(const float4*)&A4e[(j << 5) + (p << 2)];
    float  a1 = A1e[(j << 3) + p];
    fma4(d[0], a4.x, s4); fma4(d[1], a4.y, s4); fma4(d[2], a4.z, s4);
    fma4(d[3], a4.w, s4); fma4(d[4], a1,   s4);
  }
}

__device__ __forceinline__ void eacc_u(const float* __restrict__ A4e,
                                       const float* __restrict__ A1e,
                                       const float* __restrict__ S_l,
                                       int p, int c,
                                       float4 d[5])
{
  #pragma unroll 4
  for (int j = 0; j < 38; ++j) {
    float4 s4 = *(const float4*)&S_l[(j << 7) + (c << 2)];
    float4 a4 = *(const float4*)&A4e[(j << 5) + (p << 2)];
    float  a1 = A1e[(j << 3) + p];
    fma4(d[0], a4.x, s4); fma4(d[1], a4.y, s4); fma4(d[2], a4.z, s4);
    fma4(d[3], a4.w, s4); fma4(d[4], a1,   s4);
  }
}

__device__ __forceinline__ void gemm_fused(const float* __restrict__ H_l,
                                           const float* __restrict__ Wb,
                                           int p, int c, float4 g[3][5])
{
  #pragma unroll
  for (int e = 0; e < 3; ++e)
    #pragma unroll
    for (int q = 0; q < 5; ++q) { g[e][q].x = 0.f; g[e][q].y = 0.f; g[e][q].z = 0.f; g[e][q].w = 0.f; }
  #pragma unroll 1
  for (int k0 = 0; k0 < 128; k0 += 4) {
    float4 h0 = *(const float4*)&H_l[((p+ 0) << 7) + k0];
    float4 h1 = *(const float4*)&H_l[((p+ 8) << 7) + k0];
    float4 h2 = *(const float4*)&H_l[((p+16) << 7) + k0];
    float4 h3 = *(const float4*)&H_l[((p+24) << 7) + k0];
    float4 h4 = *(const float4*)&H_l[((p+32) << 7) + k0];
    #pragma unroll
    for (int e = 0; e < 3; ++e) {
      const float* We = &Wb[(e << 14) + (k0 << 7) + (c << 2)];
      float4 w0 = *(const float4*)&We[  0];
      float4 w1 = *(const float4*)&We[128];
      float4 w2 = *(const float4*)&We[256];
      float4 w3 = *(const float4*)&We[384];
      fma4(g[e][0], h0.x, w0); fma4(g[e][0], h0.y, w1); fma4(g[e][0], h0.z, w2); fma4(g[e][0], h0.w, w3);
      fma4(g[e][1], h1.x, w0); fma4(g[e][1], h1.y, w1); fma4(g[e][1], h1.z, w2); fma4(g[e][1], h1.w, w3);
      fma4(g[e][2], h2.x, w0); fma4(g[e][2], h2.y, w1); fma4(g[e][2], h2.z, w2); fma4(g[e][2], h2.w, w3);
      fma4(g[e][3], h3.x, w0); fma4(g[e][3], h3.y, w1); fma4(g[e][3], h3.z, w2); fma4(g[e][3], h3.w, w3);
      fma4(g[e][4], h4.x, w0); fma4(g[e][4], h4.y, w1); fma4(g[e][4], h4.z, w2); fma4(g[e][4], h4.w, w3);
    }
  }
}

__device__ __forceinline__ void relu_store(float* __restrict__ H_l, int p, int c,
                                           const float4 d[5])
{
  #pragma unroll
  for (int q = 0; q < 5; ++q) {
    float4 t;
    t.x = fmaxf(d[q].x, 0.f); t.y = fmaxf(d[q].y, 0.f);
    t.z = fmaxf(d[q].z, 0.f); t.w = fmaxf(d[q].w, 0.f);
    *(float4*)&H_l[((p + (q << 3)) << 7) + (c << 2)] = t;
  }
}

__global__ __launch_bounds__(256) void k_rgcn(
    const float* __restrict__ adj, const int* __restrict__ mask_node,
    const int* __restrict__ mask_edge, const int* __restrict__ isel,
    const float* __restrict__ sx, const float* __restrict__ Wt,
    float* __restrict__ sumE, float* __restrict__ sumSq,
    float* __restrict__ selw)
{
  const int br  = blockIdx.x;
  const int b   = br / R_;
  const int r   = br - b*R_;
  const int tid = threadIdx.x;
  const int c   = tid & 31;
  const int p   = tid >> 5;

  __shared__ __align__(16) float A4_l[3*1216];   // 14592 B (all 3 e, resident)
  __shared__ __align__(16) float A1_l[3*304];    //  3648 B
  __shared__ __align__(16) float SH_l[40*128];   // 20480 B (S and H, time-shared)
  __shared__ int mn_l[40];

  if (tid < 40) mn_l[tid] = (tid < 38) ? mask_node[r*N_ + tid] : 0;

  float av[5], a1v[2];
  ldA(adj, mask_edge, b, r, 0, tid, av, a1v);    // prefetch e=0
  __syncthreads();                               // mn_l visible

  float4 d[5];
  #pragma unroll
  for (int q = 0; q < 5; ++q) { d[q].x = d[q].y = d[q].z = d[q].w = 0.f; }

  // ---------------- gconv 1: S-fill + A-fill(once) + einsum, pipelined ------
  for (int e = 0; e < 3; ++e) {
    for (int idx = tid; idx < 40*32; idx += 256) {
      int j = idx >> 5, q4 = idx & 31;
      float4 v; v.x = v.y = v.z = v.w = 0.f;
      if (j < N_ && mn_l[j]) v = *(const float4*)&sx[(b*N_ + j)*384 + (e << 7) + (q4 << 2)];
      *(float4*)&SH_l[(j << 7) + (q4 << 2)] = v;
    }
    stA(&A4_l[e*1216], &A1_l[e*304], tid, av, a1v);
    __syncthreads();
    if (e < 2) ldA(adj, mask_edge, b, r, e+1, tid, av, a1v);  // hide under eacc
    eacc_m(&A4_l[e*1216], &A1_l[e*304], SH_l, p, c, mn_l, d);
    __syncthreads();                       // einsum done before S refill
  }
  relu_store(SH_l, p, c, d);               // SH now holds H (all 40 rows)
  __syncthreads();

  // ---------------- gconv 2 (gv=0) and gconv 3 (gv=1), fused-e gemm ---------
  for (int gv = 0; gv < 2; ++gv) {
    float4 g[3][5];
    gemm_fused(SH_l, &Wt[gv*49152], p, c, g);   // consumes ALL of H into regs
    #pragma unroll
    for (int q = 0; q < 5; ++q) { d[q].x = d[q].y = d[q].z = d[q].w = 0.f; }
    #pragma unroll
    for (int e = 0; e < 3; ++e) {
      __syncthreads();      // e=0: gemm H-reads done; e>0: prior eacc S-reads done
      #pragma unroll
      for (int q = 0; q < 5; ++q)
        *(float4*)&SH_l[((p + (q << 3)) << 7) + (c << 2)] = g[e][q];
      __syncthreads();
      eacc_u(&A4_l[e*1216], &A1_l[e*304], SH_l, p, c, d);
    }
    if (gv == 0) {
      __syncthreads();      // eacc (e=2) readers of SH done before H overwrite
      relu_store(SH_l, p, c, d);
      __syncthreads();      // H visible before gv=1 gemm reads it
    }
  }
  __syncthreads();   // last einsum done before SH reuse below

  // ---------------- BN partials + edge node selection ----------------
  {
    float4 sA, sB;
    sA.x = d[0].x+d[1].x+d[2].x+d[3].x+d[4].x;
    sA.y = d[0].y+d[1].y+d[2].y+d[3].y+d[4].y;
    sA.z = d[0].z+d[1].z+d[2].z+d[3].z+d[4].z;
    sA.w = d[0].w+d[1].w+d[2].w+d[3].w+d[4].w;
    sB.x = d[0].x*d[0].x+d[1].x*d[1].x+d[2].x*d[2].x+d[3].x*d[3].x+d[4].x*d[4].x;
    sB.y = d[0].y*d[0].y+d[1].y*d[1].y+d[2].y*d[2].y+d[3].y*d[3].y+d[4].y*d[4].y;
    sB.z = d[0].z*d[0].z+d[1].z*d[1].z+d[2].z*d[2].z+d[3].z*d[3].z+d[4].z*d[4].z;
    sB.w = d[0].w*d[0].w+d[1].w*d[1].w+d[2].w*d[2].w+d[3].w*d[3].w+d[4].w*d[4].w;
    *(float4*)&SH_l[( p      << 7) + (c << 2)] = sA;   // rows 0..7  : sums
    *(float4*)&SH_l[((8 + p) << 7) + (c << 2)] = sB;   // rows 8..15 : squares
  }
  __syncthreads();
  {
    int o = tid & 127, half = tid >> 7;
    float t = 0.f;
    #pragma unroll
    for (int pp = 0; pp < 8; ++pp) t += SH_l[(((half << 3) + pp) << 7) + o];
    if (half == 0) sumE [br*128 + o] = t;
    else           sumSq[br*128 + o] = t;
  }
  if (r >= N_) {
    int k  = r - N_;
    int iu = isel[2*k], ju = isel[2*k+1];
    if (p == (iu & 7)) {
      int mu = iu >> 3;
      float4 v = d[0];
      if (mu == 1) v = d[1]; else if (mu == 2) v = d[2];
      else if (mu == 3) v = d[3]; else if (mu == 4) v = d[4];
      *(float4*)&selw[(((b*NE_ + k)*2 + 0) << 7) + (c << 2)] = v;
    }
    if (p == (ju & 7)) {
      int mu = ju >> 3;
      float4 v = d[0];
      if (mu == 1) v = d[1]; else if (mu == 2) v = d[2];
      else if (mu == 3) v = d[3]; else if (mu == 4) v = d[4];
      *(float4*)&selw[(((b*NE_ + k)*2 + 1) << 7) + (c << 2)] = v;
    }
  }
}

// ============================================================================
// Kernel Z: zero the argmax-shift accumulators (ws is re-poisoned 0xAA).
// ============================================================================
__global__ __launch_bounds__(256) void k_zero(int* __restrict__ Pn,
                                              int* __restrict__ Pe)
{
  int i = blockIdx.x*256 + threadIdx.x;
  if (i < B_*N_)   Pn[i] = 0;
  if (i < B_*NE_)  Pe[i] = 0;
}

// ============================================================================
// BN statistics: two-stage deterministic f64 reduction
// ============================================================================
__global__ __launch_bounds__(256) void k_bn1(const float* __restrict__ sumE,
                                             const float* __restrict__ sumSq,
                                             double* __restrict__ part)
{
  int g = blockIdx.x;                 // 0..255, rows [g*47, g*47+47)
  int t = threadIdx.x;
  int o = t & 127, h = t >> 7;
  int lo = g*47;
  int hi = lo + 47; if (hi > BR_) hi = BR_;
  double a1 = 0.0, a2 = 0.0;
  for (int i = lo + h; i < hi; i += 2) {
    a1 += (double)sumE [i*128 + o];
    a2 += (double)sumSq[i*128 + o];
  }
  __shared__ double sh1[256], sh2[256];
  sh1[t] = a1; sh2[t] = a2;
  __syncthreads();
  if (h == 0) {
    part[g*128 + o]           = sh1[o] + sh1[128 + o];
    part[256*128 + g*128 + o] = sh2[o] + sh2[128 + o];
  }
}

__global__ __launch_bounds__(128) void k_bn2(const double* __restrict__ part,
                                             const float* __restrict__ gamma,
                                             const float* __restrict__ beta,
                                             float* __restrict__ bnsc,
                                             float* __restrict__ bnsh)
{
  int o = threadIdx.x;
  double s1 = 0.0, s2 = 0.0;
  for (int g = 0; g < 256; ++g) {
    s1 += part[g*128 + o];
    s2 += part[256*128 + g*128 + o];
  }
  double cnt = (double)BR_ * 38.0;
  double m   = s1 / cnt;
  double var = s2 / cnt - m*m;
  double rs  = 1.0 / sqrt(var + 1e-5);
  double sc  = (double)gamma[o] * rs;
  bnsc[o] = (float)sc;
  bnsh[o] = beta[o] - (float)(m * sc);
}

// ============================================================================
// Kernel D: node discretization, layer-parallel (round-11).
// ============================================================================
__global__ __launch_bounds__(128) void k_node_par(
    const float* __restrict__ sumE, const float* __restrict__ bnsc,
    const float* __restrict__ bnsh,
    const float* __restrict__ w1t_n, const float* __restrict__ b1,
    const float* __restrict__ w2, const float* __restrict__ b2,
    int* __restrict__ Pn)
{
  int blk = blockIdx.x;               // l*608 + bn
  int l   = blk / (B_*N_);
  int bn  = blk - l*(B_*N_);
  int b   = bn / N_;
  int o   = threadIdx.x;
  __shared__ __align__(16) float xv[128];
  __shared__ __align__(16) float hb[128];
  __shared__ float lg[NT_];
  int br = b*R_ + (bn - b*N_);        // r = n
  xv[o] = sumE[br*128 + o]*bnsc[o] + 38.f*bnsh[o];
  __syncthreads();
  const float* wb = &w1t_n[l << 14];
  float s = b1[l*128 + o];
  #pragma unroll 2
  for (int k = 0; k < 128; k += 4) {
    float4 x4 = *(const float4*)&xv[k];       // LDS broadcast
    s += wb[((k+0) << 7) + o]*x4.x + wb[((k+1) << 7) + o]*x4.y
       + wb[((k+2) << 7) + o]*x4.z + wb[((k+3) << 7) + o]*x4.w;
  }
  hb[o] = tanhf(s);
  __syncthreads();
  if (o < NT_) {
    const float* w2r = &w2[(l*NT_ + o)*128];
    float s2 = b2[l*NT_ + o];
    for (int k = 0; k < 128; ++k) s2 += w2r[k]*hb[k];
    lg[o] = s2;
  }
  __syncthreads();
  if (o == 0) {
    int best = 0; float bv = lg[0];
    #pragma unroll
    for (int cc = 1; cc < NT_; ++cc) if (lg[cc] > bv) { bv = lg[cc]; best = cc; }
    atomicAdd(&Pn[bn], best);
  }
}

// ============================================================================
// Kernel E (round-12): edge discretization, layer-parallel, 128 threads,
// 4 batches/thread.  Round-11's 256-thr version re-read the 196 KB layer
// weight stream once per batch-PAIR (8x/block, 1536 VMEM b128). Mapping
// c=t&31 (o-cols 4c..4c+3), p=t>>5 in 0..3 owning batches {p,p+4,p+8,p+12}
// halves that to 768/block with the same LDS broadcast total (xv reads are
// 2-row aliased across the wave — free). ~60 live VGPR, no spill.
// ============================================================================
__global__ __launch_bounds__(128) void k_edge_par(
    const float* __restrict__ sumE, const float* __restrict__ selw,
    const float* __restrict__ bnsc, const float* __restrict__ bnsh,
    const float* __restrict__ w1t_e, const float* __restrict__ b1,
    const float* __restrict__ w2, const float* __restrict__ b2,
    int* __restrict__ Pe)
{
  int blk = blockIdx.x;               // l*NE + k
  int l = blk / NE_;
  int k = blk - l*NE_;
  int t = threadIdx.x;
  int c = t & 31, p = t >> 5;         // p in 0..3
  __shared__ __align__(16) float xv[16][384];
  __shared__ __align__(16) float hb[16][132];
  __shared__ float lg[16][4];

  for (int idx = t; idx < 16*128; idx += 128) {
    int b = idx >> 7, oo = idx & 127;
    float sc = bnsc[oo], sh = bnsh[oo];
    int base = ((b*NE_ + k)*2)*128;
    xv[b][oo]       = selw[base + oo]      *sc + sh;
    xv[b][128 + oo] = selw[base + 128 + oo]*sc + sh;
    xv[b][256 + oo] = sumE[(b*R_ + N_ + k)*128 + oo]*sc + 38.f*sh;
  }
  __syncthreads();

  float4 acc[4];
  {
    float4 bb4 = *(const float4*)&b1[(l << 7) + (c << 2)];
    acc[0] = bb4; acc[1] = bb4; acc[2] = bb4; acc[3] = bb4;
  }
  const float* wl = &w1t_e[(l*384) << 7];
  #pragma unroll 2
  for (int kk = 0; kk < 384; kk += 4) {
    const float* wk = wl + (kk << 7) + (c << 2);
    float4 w0 = *(const float4*)&wk[  0];         // coalesced 512B
    float4 w1 = *(const float4*)&wk[128];
    float4 w2v= *(const float4*)&wk[256];
    float4 w3 = *(const float4*)&wk[384];
    #pragma unroll
    for (int m = 0; m < 4; ++m) {
      float4 x = *(const float4*)&xv[p + (m << 2)][kk];   // 2-row aliased b128
      fma4(acc[m], x.x, w0); fma4(acc[m], x.y, w1);
      fma4(acc[m], x.z, w2v); fma4(acc[m], x.w, w3);
    }
  }
  #pragma unroll
  for (int m = 0; m < 4; ++m) {
    float4 h;
    h.x = tanhf(acc[m].x); h.y = tanhf(acc[m].y);
    h.z = tanhf(acc[m].z); h.w = tanhf(acc[m].w);
    *(float4*)&hb[p + (m << 2)][c << 2] = h;
  }
  __syncthreads();
  if (t < 64) {
    int m = t >> 2, c2 = t & 3;
    const float* w2r = &w2[(l*ET_ + c2)*128];
    float s2 = b2[l*ET_ + c2];
    for (int kk = 0; kk < 128; ++kk) s2 += w2r[kk]*hb[m][kk];
    lg[m][c2] = s2;
  }
  __syncthreads();
  if (t < 16) {
    int best = 0; float bv = lg[t][0];
    #pragma unroll
    for (int cc = 1; cc < ET_; ++cc) if (lg[t][cc] > bv) { bv = lg[t][cc]; best = cc; }
    atomicAdd(&Pe[t*NE_ + k], best);
  }
}

// ============================================================================
// Kernel G: apply the accumulated circular shifts (node then edge blocks).
// ============================================================================
__global__ __launch_bounds__(64) void k_gather(
    const int* __restrict__ Pn, const int* __restrict__ Pe,
    const float* __restrict__ x_deq, const float* __restrict__ adj_deq,
    float* __restrict__ out)
{
  int blk = blockIdx.x;
  int t   = threadIdx.x;
  if (blk < B_*N_) {
    if (t < NT_) {
      int P = Pn[blk] % NT_;
      int src = t - P; if (src < 0) src += NT_;
      out[blk*NT_ + t] = x_deq[blk*NT_ + src];
    }
  } else {
    int k = blk - B_*N_;
    int m = t >> 2, c2 = t & 3;
    int P = Pe[m*NE_ + k] & 3;
    int src = c2 - P; if (src < 0) src += ET_;
    out[B_*N_*NT_ + (m*NE_ + k)*ET_ + c2] = adj_deq[(m*NE_ + k)*ET_ + src];
  }
}

// ============================================================================
extern "C" void kernel_launch(void* const* d_in, const int* in_sizes, int n_in,
                              void* d_out, int out_size, void* d_ws, size_t ws_size,
                              hipStream_t stream)
{
  (void)in_sizes; (void)n_in; (void)out_size; (void)ws_size;

  const float* x         = (const float*)d_in[0];
  const float* adj       = (const float*)d_in[1];
  const float* x_deq     = (const float*)d_in[2];
  const float* adj_deq   = (const float*)d_in[3];
  const int*   mask_node = (const int*)d_in[4];
  const int*   mask_edge = (const int*)d_in[5];
  const int*   isel      = (const int*)d_in[6];
  const float* emb_w     = (const float*)d_in[7];
  const float* gc1_w     = (const float*)d_in[8];
  const float* gc2_w     = (const float*)d_in[9];
  const float* gc3_w     = (const float*)d_in[10];
  const float* bn_gamma  = (const float*)d_in[11];
  const float* bn_beta   = (const float*)d_in[12];
  const float* node_w1   = (const float*)d_in[13];
  const float* node_b1   = (const float*)d_in[14];
  const float* node_w2   = (const float*)d_in[15];
  const float* node_b2   = (const float*)d_in[16];
  const float* edge_w1   = (const float*)d_in[17];
  const float* edge_b1   = (const float*)d_in[18];
  const float* edge_w2   = (const float*)d_in[19];
  const float* edge_b2   = (const float*)d_in[20];

  float* out_f = (float*)d_out;

  // Workspace layout (~25 MB). Three overlays, all safe by stream order:
  //  - Wt (393 KB) overlays `part` (524 KB): consumed by k_rgcn < k_bn1.
  //  - w1t_e/w1t_n overlay sumSq: dead after k_bn1; k_wt2 launches after.
  //  - Pn/Pe (ints) overlay sx: dead after k_rgcn; k_zero launches after.
  float*  wsf   = (float*)d_ws;
  float*  sx    = wsf;                      // 608*384       = 233472
  float*  sumE  = sx    + 233472;           // 11856*128     = 1517568
  float*  sumSq = sumE  + 1517568;          // 1517568
  float*  selw  = sumSq + 1517568;          // 16*703*2*128  = 2879488
  float*  bnsc  = selw  + 2879488;          // 128
  float*  bnsh  = bnsc  + 128;              // 128
  double* part  = (double*)(bnsh + 128);    // 2*256*128 doubles
  float*  Wt    = (float*)part;             // 98304 floats (overlay #1)
  float*  w1t_e = sumSq;                    // 589824 floats (overlay #2)
  float*  w1t_n = sumSq + 589824;           // 196608 floats
  int*    Pn    = (int*)sx;                 // 608 ints      (overlay #3)
  int*    Pe    = Pn + B_*N_;               // 11248 ints

  k_wt      <<<768,           128, 0, stream>>>(gc2_w, gc3_w, Wt);
  k_sx      <<<B_*N_,         128, 0, stream>>>(x, emb_w, gc1_w, sx);
  k_rgcn    <<<BR_,           256, 0, stream>>>(adj, mask_node, mask_edge, isel,
                                                sx, Wt, sumE, sumSq, selw);
  k_zero    <<<(B_*NE_ + 255)/256, 256, 0, stream>>>(Pn, Pe);
  k_bn1     <<<256,           256, 0, stream>>>(sumE, sumSq, part);
  k_bn2     <<<1,             128, 0, stream>>>(part, bn_gamma, bn_beta, bnsc, bnsh);
  k_wt2     <<<12*384+12*128, 128, 0, stream>>>(node_w1, edge_w1, w1t_e, w1t_n);
  k_node_par<<<L_*B_*N_,      128, 0, stream>>>(sumE, bnsc, bnsh, w1t_n, node_b1,
                                                node_w2, node_b2, Pn);
  k_edge_par<<<L_*NE_,        128, 0, stream>>>(sumE, selw, bnsc, bnsh, w1t_e,
                                                edge_b1, edge_w2, edge_b2, Pe);
  k_gather  <<<B_*N_ + NE_,    64, 0, stream>>>(Pn, Pe, x_deq, adj_deq, out_f);
}